// Round 7
// baseline (222.183 us; speedup 1.0000x reference)
//
#include <hip/hip_runtime.h>

#define NV 163842          // vertices
#define NC 128             // channels
#define KN 7               // neighbors (incl. self)
#define NWELT (NC * KN * NC)  // 114688 elements per W
#define BN_EPS 1e-5f
#define NBLK 1281          // ceil(NV/128)
#define RG 32              // reduce groups
#define RROWS 41           // ceil(NBLK/RG)

typedef __attribute__((ext_vector_type(4))) float f32x4;
typedef __attribute__((ext_vector_type(8))) short bf16x8;
typedef __attribute__((ext_vector_type(8))) unsigned short u16x8;

static __device__ __forceinline__ unsigned short f2bf(float f) {
    union { float f; unsigned int u; } v; v.f = f;
    unsigned int r = v.u + 0x7fffu + ((v.u >> 16) & 1u);
    return (unsigned short)(r >> 16);
}
static __device__ __forceinline__ float bf2f(unsigned short s) {
    union { unsigned int u; float f; } v; v.u = ((unsigned int)s) << 16;
    return v.f;
}
static __device__ __forceinline__ void gload_lds16(const void* g, void* l) {
    __builtin_amdgcn_global_load_lds((const __attribute__((address_space(1))) void*)g,
                                     (__attribute__((address_space(3))) void*)l, 16, 0, 0);
}

// ---- kernel 1: fp32 -> bf16 for x, W1, W2 ----
__global__ void cvt_kernel(const float* __restrict__ x, const float* __restrict__ w1,
                           const float* __restrict__ w2, unsigned short* __restrict__ xbf,
                           unsigned short* __restrict__ w1bf, unsigned short* __restrict__ w2bf)
{
    const int total4 = (NV * NC + 2 * NWELT) / 4;
    for (int i = blockIdx.x * blockDim.x + threadIdx.x; i < total4; i += gridDim.x * blockDim.x) {
        int e = i * 4;
        const float* src; unsigned short* dst;
        if (e < NV * NC)              { src = x  + e;                  dst = xbf  + e; }
        else if (e < NV * NC + NWELT) { src = w1 + (e - NV * NC);      dst = w1bf + (e - NV * NC); }
        else                          { src = w2 + (e - NV * NC - NWELT); dst = w2bf + (e - NV * NC - NWELT); }
        float4 v = *(const float4*)src;
        ushort4 o;
        o.x = f2bf(v.x); o.y = f2bf(v.y); o.z = f2bf(v.z); o.w = f2bf(v.w);
        *(ushort4*)dst = o;
    }
}

// ---- conv kernel: gathered bf16 GEMM, 128x128 tile, 14 K-chunks of 64 ----
// Round-3 skeleton (8 waves, 64x32/wave, gload_lds staging, pre-swizzled source)
// with pipeline depth 3: 4 LDS slots x 32KB = 128KB, counted vmcnt (T3/T4) —
// STAGE(c+3) issued at iter c; wait only for STAGE(c+1) at iter end (vmcnt(8)).
__global__ __launch_bounds__(512, 2)
void conv_kernel(const unsigned short* __restrict__ xin,   // bf16 [NV][128]
                 const int* __restrict__ neigh,            // [NV*7]
                 const unsigned short* __restrict__ wbf,   // bf16 [128][896]
                 unsigned short* __restrict__ hout,        // bf16 [NV][128]
                 float* __restrict__ psum, float* __restrict__ psq)  // [NBLK][128]
{
    // 4 slots x (A 16KB @0 + B 16KB @16384) = 128KB
    __shared__ __align__(16) char smem[131072];

    const int t    = threadIdx.x;
    const int row0 = blockIdx.x * 128;
    const int w    = t >> 6;
    const int lane = t & 63;
    const int lrow = lane & 15;
    const int lgrp = lane >> 4;
    const int wr   = w >> 2;         // 0..1 -> 64-row half
    const int wc   = w & 3;          // 0..3 -> 32-col quarter

    const int sl   = lane & 7;       // 16B slot within 128B row-chunk
    const int r3   = lane >> 3;      // row within 8-row group (== row&7)
    const int srcoff = (sl ^ r3) << 4;   // pre-swizzled source byte offset

    // rows this lane stages, clamped for the tail block
    const int rA0 = w * 16 + r3;
    const int g0  = (row0 + rA0     < NV) ? (row0 + rA0)     : (NV - 1);
    const int g1  = (row0 + rA0 + 8 < NV) ? (row0 + rA0 + 8) : (NV - 1);

    int idx0[KN], idx1[KN];
    #pragma unroll
    for (int k = 0; k < KN; ++k) {
        idx0[k] = neigh[g0 * KN + k];
        idx1[k] = neigh[g1 * KN + k];
    }

    const char* xinb = (const char*)xin;
    const char* bsrc0 = (const char*)wbf + (size_t)(w * 16 + r3) * 1792 + srcoff;
    const char* bsrc1 = (const char*)wbf + (size_t)(w * 16 + 8 + r3) * 1792 + srcoff;

    f32x4 acc[4][2];
    #pragma unroll
    for (int mf = 0; mf < 4; ++mf)
        #pragma unroll
        for (int nf = 0; nf < 2; ++nf)
            acc[mf][nf] = (f32x4){0.f, 0.f, 0.f, 0.f};

    // chunk c: neighbor k_=c>>1, 128B row-half h_=c&1; slot (c&3)
#define STAGE(c) do {                                                                 \
        const int k_ = (c) >> 1, h_ = (c) & 1;                                        \
        char* lA = smem + ((c) & 3) * 32768 + w * 2048;                               \
        char* lB = lA + 16384;                                                        \
        gload_lds16(xinb + (size_t)idx0[k_] * 256 + h_ * 128 + srcoff, lA);           \
        gload_lds16(xinb + (size_t)idx1[k_] * 256 + h_ * 128 + srcoff, lA + 1024);    \
        gload_lds16(bsrc0 + k_ * 256 + h_ * 128, lB);                                 \
        gload_lds16(bsrc1 + k_ * 256 + h_ * 128, lB + 1024);                          \
    } while (0)

    // prologue: stage chunks 0..2 (12 loads/thread); wait chunk 0 -> vmcnt(8)
    STAGE(0); STAGE(1); STAGE(2);
    asm volatile("s_waitcnt vmcnt(8)" ::: "memory");
    __builtin_amdgcn_sched_barrier(0);
    __builtin_amdgcn_s_barrier();
    __builtin_amdgcn_sched_barrier(0);

    #pragma unroll
    for (int c = 0; c < 14; ++c) {
        if (c < 11) STAGE(c + 3);
        __builtin_amdgcn_sched_barrier(0);

        const char* Ab = smem + (c & 3) * 32768;
        const char* Bb = Ab + 16384;
        #pragma unroll
        for (int ks = 0; ks < 2; ++ks) {
            const int koff = ks * 64 + lgrp * 16;
            bf16x8 a[4], b[2];
            #pragma unroll
            for (int mf = 0; mf < 4; ++mf) {
                const int arow = wr * 64 + mf * 16 + lrow;
                a[mf] = *(const bf16x8*)(Ab + ((arow * 128 + koff) ^ ((arow & 7) << 4)));
            }
            #pragma unroll
            for (int nf = 0; nf < 2; ++nf) {
                const int bcol = wc * 32 + nf * 16 + lrow;
                b[nf] = *(const bf16x8*)(Bb + ((bcol * 128 + koff) ^ ((bcol & 7) << 4)));
            }
            #pragma unroll
            for (int mf = 0; mf < 4; ++mf) {
                acc[mf][0] = __builtin_amdgcn_mfma_f32_16x16x32_bf16(a[mf], b[0], acc[mf][0], 0, 0, 0);
                acc[mf][1] = __builtin_amdgcn_mfma_f32_16x16x32_bf16(a[mf], b[1], acc[mf][1], 0, 0, 0);
            }
        }

        if (c < 13) {
            __builtin_amdgcn_sched_barrier(0);
            // counted wait: ensure STAGE(c+1) complete; younger loads stay in flight.
            //   c<=10: chunks c+2,c+3 outstanding -> vmcnt(8)
            //   c==11: chunk 13 outstanding       -> vmcnt(4)
            //   c==12: none younger               -> vmcnt(0)
            if (c <= 10)      asm volatile("s_waitcnt vmcnt(8)" ::: "memory");
            else if (c == 11) asm volatile("s_waitcnt vmcnt(4)" ::: "memory");
            else              asm volatile("s_waitcnt vmcnt(0)" ::: "memory");
            __builtin_amdgcn_sched_barrier(0);
            __builtin_amdgcn_s_barrier();
            __builtin_amdgcn_sched_barrier(0);
        }
    }
#undef STAGE

    // ---- epilogue: store bf16 h, block-reduce per-channel sum/sumsq (masked tail) ----
    // redsum/redsq live in slot0 [0,2048); chunk 13 read slot 1 — disjoint, and
    // slot 0's last reader (chunk 12) is fenced by the end-of-iter-12 barrier.
    float* redsum = (float*)smem;            // [2][128]
    float* redsq  = (float*)(smem + 1024);   // [2][128]

    #pragma unroll
    for (int nf = 0; nf < 2; ++nf) {
        const int col = wc * 32 + nf * 16 + lrow;
        float sum = 0.f, sq = 0.f;
        #pragma unroll
        for (int mf = 0; mf < 4; ++mf) {
            const int rbase = row0 + wr * 64 + mf * 16 + lgrp * 4;
            #pragma unroll
            for (int r = 0; r < 4; ++r) {
                float v = acc[mf][nf][r];
                const int grow = rbase + r;
                if (grow < NV) {
                    sum += v; sq += v * v;
                    hout[(size_t)grow * NC + col] = f2bf(v);
                }
            }
        }
        sum += __shfl_xor(sum, 16); sum += __shfl_xor(sum, 32);
        sq  += __shfl_xor(sq, 16);  sq  += __shfl_xor(sq, 32);
        if (lgrp == 0) { redsum[wr * 128 + col] = sum; redsq[wr * 128 + col] = sq; }
    }
    __syncthreads();
    if (t < 128) {
        psum[(size_t)blockIdx.x * 128 + t] = redsum[t] + redsum[128 + t];
        psq[(size_t)blockIdx.x * 128 + t]  = redsq[t]  + redsq[128 + t];
    }
}

// ---- deterministic two-level stats reduction ----
__global__ void bn_reduce_kernel(const float* __restrict__ psum, const float* __restrict__ psq,
                                 float* __restrict__ psum2, float* __restrict__ psq2)
{
    const int c = threadIdx.x;   // 128
    const int g = blockIdx.x;    // RG
    const int b0 = g * RROWS;
    const int b1 = (b0 + RROWS < NBLK) ? b0 + RROWS : NBLK;
    float s = 0.f, q = 0.f;
    for (int b = b0; b < b1; ++b) {
        s += psum[b * 128 + c];
        q += psq[b * 128 + c];
    }
    psum2[g * 128 + c] = s;
    psq2[g * 128 + c]  = q;
}

__global__ void bn_finalize_kernel(const float* __restrict__ psum2, const float* __restrict__ psq2,
                                   const float* __restrict__ gamma, const float* __restrict__ beta,
                                   float* __restrict__ scale, float* __restrict__ shift)
{
    const int c = threadIdx.x;
    float s = 0.f, q = 0.f;
    #pragma unroll
    for (int g = 0; g < RG; ++g) { s += psum2[g * 128 + c]; q += psq2[g * 128 + c]; }
    const float inv  = 1.f / (float)NV;
    const float mean = s * inv;
    const float var  = q * inv - mean * mean;
    const float sc   = gamma[c] * rsqrtf(var + BN_EPS);
    scale[c] = sc;
    shift[c] = beta[c] - mean * sc;
}

// ---- apply BN1 + leaky, bf16 -> bf16 ----
__global__ void bn_apply_kernel(const unsigned short* __restrict__ h, const float* __restrict__ scale,
                                const float* __restrict__ shift, unsigned short* __restrict__ outbf)
{
    __shared__ float ssc[NC], ssh[NC];
    if (threadIdx.x < NC) { ssc[threadIdx.x] = scale[threadIdx.x]; ssh[threadIdx.x] = shift[threadIdx.x]; }
    __syncthreads();
    const int total8 = NV * NC / 8;
    for (int i = blockIdx.x * blockDim.x + threadIdx.x; i < total8; i += gridDim.x * blockDim.x) {
        const int e = i * 8;
        const int c0 = e & (NC - 1);
        u16x8 v = *(const u16x8*)(h + e);
        u16x8 o;
        #pragma unroll
        for (int j = 0; j < 8; ++j) {
            float a = bf2f(v[j]) * ssc[c0 + j] + ssh[c0 + j];
            a = a >= 0.f ? a : 0.2f * a;
            o[j] = f2bf(a);
        }
        *(u16x8*)(outbf + e) = o;
    }
}

// ---- final: out = leaky(bn2(h2_bf16) + residual); residual from bf16 x if use_bf ----
__global__ void final_kernel(const unsigned short* __restrict__ h, const float* __restrict__ x,
                             const unsigned short* __restrict__ xb, const int use_bf,
                             const float* __restrict__ scale, const float* __restrict__ shift,
                             float* __restrict__ out)
{
    __shared__ float ssc[NC], ssh[NC];
    if (threadIdx.x < NC) { ssc[threadIdx.x] = scale[threadIdx.x]; ssh[threadIdx.x] = shift[threadIdx.x]; }
    __syncthreads();
    const int total8 = NV * NC / 8;
    for (int i = blockIdx.x * blockDim.x + threadIdx.x; i < total8; i += gridDim.x * blockDim.x) {
        const int e = i * 8;
        const int c0 = e & (NC - 1);
        u16x8 v = *(const u16x8*)(h + e);
        float xv[8];
        if (use_bf) {
            u16x8 xvb = *(const u16x8*)(xb + e);
            #pragma unroll
            for (int j = 0; j < 8; ++j) xv[j] = bf2f(xvb[j]);
        } else {
            float4 x0 = *(const float4*)(x + e);
            float4 x1 = *(const float4*)(x + e + 4);
            xv[0]=x0.x; xv[1]=x0.y; xv[2]=x0.z; xv[3]=x0.w;
            xv[4]=x1.x; xv[5]=x1.y; xv[6]=x1.z; xv[7]=x1.w;
        }
        float ov[8];
        #pragma unroll
        for (int j = 0; j < 8; ++j) {
            float a = bf2f(v[j]) * ssc[c0 + j] + ssh[c0 + j] + xv[j];
            ov[j] = a >= 0.f ? a : 0.2f * a;
        }
        float4 o0 = {ov[0], ov[1], ov[2], ov[3]};
        float4 o1 = {ov[4], ov[5], ov[6], ov[7]};
        *(float4*)(out + e)     = o0;
        *(float4*)(out + e + 4) = o1;
    }
}

extern "C" void kernel_launch(void* const* d_in, const int* in_sizes, int n_in,
                              void* d_out, int out_size, void* d_ws, size_t ws_size,
                              hipStream_t stream)
{
    const float* x      = (const float*)d_in[0];
    const int*   neigh  = (const int*)d_in[1];
    const float* W1     = (const float*)d_in[2];
    // d_in[3] = b1 (cancels through BN)
    const float* gamma1 = (const float*)d_in[4];
    const float* beta1  = (const float*)d_in[5];
    const float* W2     = (const float*)d_in[6];
    // d_in[7] = b2 (cancels through BN)
    const float* gamma2 = (const float*)d_in[8];
    const float* beta2  = (const float*)d_in[9];

    // d_out (84MB fp32) doubles as two bf16 scratch halves until final_kernel.
    unsigned short* h1pre = (unsigned short*)d_out;                    // bf16 [NV][128]
    unsigned short* h1bn  = (unsigned short*)d_out + (size_t)NV * NC;  // bf16 [NV][128]
    float* out = (float*)d_out;

    char* ws = (char*)d_ws;
    size_t off = 0;
    unsigned short* xbf  = (unsigned short*)(ws + off); off += (size_t)NV * NC * 2;
    unsigned short* w1bf = (unsigned short*)(ws + off); off += NWELT * 2;
    unsigned short* w2bf = (unsigned short*)(ws + off); off += NWELT * 2;
    float* psum  = (float*)(ws + off); off += (size_t)NBLK * 128 * 4;
    float* psq   = (float*)(ws + off); off += (size_t)NBLK * 128 * 4;
    float* psum2 = (float*)(ws + off); off += RG * 128 * 4;
    float* psq2  = (float*)(ws + off); off += RG * 128 * 4;
    float* scale1 = (float*)(ws + off); off += 512;
    float* shift1 = (float*)(ws + off); off += 512;
    float* scale2 = (float*)(ws + off); off += 512;
    float* shift2 = (float*)(ws + off); off += 512;

    // If ws has room for a dedicated h2 buffer, keep xbf alive and use bf16 x
    // for the residual (saves 42MB of fp32 x re-read). Deterministic in ws_size.
    const size_t h2_bytes = (size_t)NV * NC * 2;
    unsigned short* h2pre;
    int use_bf;
    if (off + h2_bytes <= ws_size) { h2pre = (unsigned short*)(ws + off); use_bf = 1; }
    else                           { h2pre = xbf;                        use_bf = 0; }

    cvt_kernel<<<2048, 256, 0, stream>>>(x, W1, W2, xbf, w1bf, w2bf);
    conv_kernel<<<NBLK, 512, 0, stream>>>(xbf, neigh, w1bf, h1pre, psum, psq);
    bn_reduce_kernel<<<RG, 128, 0, stream>>>(psum, psq, psum2, psq2);
    bn_finalize_kernel<<<1, 128, 0, stream>>>(psum2, psq2, gamma1, beta1, scale1, shift1);
    bn_apply_kernel<<<2048, 256, 0, stream>>>(h1pre, scale1, shift1, h1bn);
    conv_kernel<<<NBLK, 512, 0, stream>>>(h1bn, neigh, w2bf, h2pre, psum, psq);
    bn_reduce_kernel<<<RG, 128, 0, stream>>>(psum, psq, psum2, psq2);
    bn_finalize_kernel<<<1, 128, 0, stream>>>(psum2, psq2, gamma2, beta2, scale2, shift2);
    final_kernel<<<2048, 256, 0, stream>>>(h2pre, x, xbf, use_bf, scale2, shift2, out);
}

// Round 8
// 187.094 us; speedup vs baseline: 1.1876x; 1.1876x over previous
//
#include <hip/hip_runtime.h>

#define NV 163842          // vertices
#define NC 128             // channels
#define KN 7               // neighbors (incl. self)
#define NWELT (NC * KN * NC)  // 114688 elements per W
#define BN_EPS 1e-5f
#define NBLK 1281          // ceil(NV/128)

typedef __attribute__((ext_vector_type(4))) float f32x4;
typedef __attribute__((ext_vector_type(8))) short bf16x8;
typedef __attribute__((ext_vector_type(8))) unsigned short u16x8;

static __device__ __forceinline__ unsigned short f2bf(float f) {
    union { float f; unsigned int u; } v; v.f = f;
    unsigned int r = v.u + 0x7fffu + ((v.u >> 16) & 1u);
    return (unsigned short)(r >> 16);
}
static __device__ __forceinline__ float bf2f(unsigned short s) {
    union { unsigned int u; float f; } v; v.u = ((unsigned int)s) << 16;
    return v.f;
}
static __device__ __forceinline__ void gload_lds16(const void* g, void* l) {
    __builtin_amdgcn_global_load_lds((const __attribute__((address_space(1))) void*)g,
                                     (__attribute__((address_space(3))) void*)l, 16, 0, 0);
}

// ---- kernel 1: fp32 -> bf16 for x, W1, W2 ----
__global__ void cvt_kernel(const float* __restrict__ x, const float* __restrict__ w1,
                           const float* __restrict__ w2, unsigned short* __restrict__ xbf,
                           unsigned short* __restrict__ w1bf, unsigned short* __restrict__ w2bf)
{
    const int total4 = (NV * NC + 2 * NWELT) / 4;
    for (int i = blockIdx.x * blockDim.x + threadIdx.x; i < total4; i += gridDim.x * blockDim.x) {
        int e = i * 4;
        const float* src; unsigned short* dst;
        if (e < NV * NC)              { src = x  + e;                  dst = xbf  + e; }
        else if (e < NV * NC + NWELT) { src = w1 + (e - NV * NC);      dst = w1bf + (e - NV * NC); }
        else                          { src = w2 + (e - NV * NC - NWELT); dst = w2bf + (e - NV * NC - NWELT); }
        float4 v = *(const float4*)src;
        ushort4 o;
        o.x = f2bf(v.x); o.y = f2bf(v.y); o.z = f2bf(v.z); o.w = f2bf(v.w);
        *(ushort4*)dst = o;
    }
}

// ---- conv kernel: gathered bf16 GEMM, 128x128 tile, 14 K-chunks of 64 ----
// R3-exact structure (best measured: 59.8us): double-buffered 64KB LDS staged via
// global_load_lds (pre-swizzled gather source), one vmcnt(0)+barrier per chunk,
// 8 waves of 64x32 output each, 2 blocks/CU.
__global__ __launch_bounds__(512, 4)
void conv_kernel(const unsigned short* __restrict__ xin,   // bf16 [NV][128]
                 const int* __restrict__ neigh,            // [NV*7]
                 const unsigned short* __restrict__ wbf,   // bf16 [128][896]
                 unsigned short* __restrict__ hout,        // bf16 [NV][128]
                 float* __restrict__ psum, float* __restrict__ psq)  // [NBLK][128]
{
    // LDS: A0 @0 (16K), B0 @16K, A1 @32K, B1 @48K
    __shared__ __align__(16) char smem[65536];

    const int t    = threadIdx.x;
    const int row0 = blockIdx.x * 128;
    const int w    = t >> 6;
    const int lane = t & 63;
    const int lrow = lane & 15;
    const int lgrp = lane >> 4;
    const int wr   = w >> 2;         // 0..1 -> 64-row half
    const int wc   = w & 3;          // 0..3 -> 32-col quarter

    const int sl   = lane & 7;       // 16B slot within 128B row-chunk
    const int r3   = lane >> 3;      // row within 8-row group (== row&7)
    const int srcoff = (sl ^ r3) << 4;   // pre-swizzled source byte offset

    // rows this lane stages (A-load j=0/1), clamped for the tail block
    const int rA0 = w * 16 + r3;
    const int g0  = (row0 + rA0     < NV) ? (row0 + rA0)     : (NV - 1);
    const int g1  = (row0 + rA0 + 8 < NV) ? (row0 + rA0 + 8) : (NV - 1);

    int idx0[KN], idx1[KN];
    #pragma unroll
    for (int k = 0; k < KN; ++k) {
        idx0[k] = neigh[g0 * KN + k];
        idx1[k] = neigh[g1 * KN + k];
    }

    const char* xinb = (const char*)xin;
    const char* bsrc0 = (const char*)wbf + (size_t)(w * 16 + r3) * 1792 + srcoff;
    const char* bsrc1 = (const char*)wbf + (size_t)(w * 16 + 8 + r3) * 1792 + srcoff;

    f32x4 acc[4][2];
    #pragma unroll
    for (int mf = 0; mf < 4; ++mf)
        #pragma unroll
        for (int nf = 0; nf < 2; ++nf)
            acc[mf][nf] = (f32x4){0.f, 0.f, 0.f, 0.f};

#define STAGE(c) do {                                                              \
        const int h_ = (c) & 1, k_ = (c) >> 1, bs_ = ((c) & 1) * 32768;            \
        char* lA = smem + bs_ + w * 2048;                                          \
        char* lB = smem + bs_ + 16384 + w * 2048;                                  \
        gload_lds16(xinb + (size_t)idx0[k_] * 256 + h_ * 128 + srcoff, lA);        \
        gload_lds16(xinb + (size_t)idx1[k_] * 256 + h_ * 128 + srcoff, lA + 1024); \
        gload_lds16(bsrc0 + k_ * 256 + h_ * 128, lB);                              \
        gload_lds16(bsrc1 + k_ * 256 + h_ * 128, lB + 1024);                       \
    } while (0)

    STAGE(0);
    asm volatile("s_waitcnt vmcnt(0)" ::: "memory");
    __builtin_amdgcn_s_barrier();
    __builtin_amdgcn_sched_barrier(0);

    #pragma unroll
    for (int c = 0; c < 14; ++c) {
        if (c < 13) STAGE(c + 1);

        const char* Ab = smem + (c & 1) * 32768;
        const char* Bb = Ab + 16384;
        #pragma unroll
        for (int ks = 0; ks < 2; ++ks) {
            const int koff = ks * 64 + lgrp * 16;
            bf16x8 a[4], b[2];
            #pragma unroll
            for (int mf = 0; mf < 4; ++mf) {
                const int arow = wr * 64 + mf * 16 + lrow;
                a[mf] = *(const bf16x8*)(Ab + ((arow * 128 + koff) ^ ((arow & 7) << 4)));
            }
            #pragma unroll
            for (int nf = 0; nf < 2; ++nf) {
                const int bcol = wc * 32 + nf * 16 + lrow;
                b[nf] = *(const bf16x8*)(Bb + ((bcol * 128 + koff) ^ ((bcol & 7) << 4)));
            }
            #pragma unroll
            for (int mf = 0; mf < 4; ++mf) {
                acc[mf][0] = __builtin_amdgcn_mfma_f32_16x16x32_bf16(a[mf], b[0], acc[mf][0], 0, 0, 0);
                acc[mf][1] = __builtin_amdgcn_mfma_f32_16x16x32_bf16(a[mf], b[1], acc[mf][1], 0, 0, 0);
            }
        }

        if (c < 13) {
            asm volatile("s_waitcnt vmcnt(0)" ::: "memory");
            __builtin_amdgcn_sched_barrier(0);
            __builtin_amdgcn_s_barrier();
            __builtin_amdgcn_sched_barrier(0);
        }
    }
#undef STAGE

    // ---- epilogue: store bf16 h, block-reduce per-channel sum/sumsq (masked tail) ----
    // redsum/redsq in buf0 [0,2048); last chunk (c=13) read buf1 @32768 — disjoint,
    // and buf0's last reader (chunk 12) is fenced by the end-of-iter-12 barrier.
    float* redsum = (float*)smem;            // [2][128]
    float* redsq  = (float*)(smem + 1024);   // [2][128]

    #pragma unroll
    for (int nf = 0; nf < 2; ++nf) {
        const int col = wc * 32 + nf * 16 + lrow;
        float sum = 0.f, sq = 0.f;
        #pragma unroll
        for (int mf = 0; mf < 4; ++mf) {
            const int rbase = row0 + wr * 64 + mf * 16 + lgrp * 4;
            #pragma unroll
            for (int r = 0; r < 4; ++r) {
                float v = acc[mf][nf][r];
                const int grow = rbase + r;
                if (grow < NV) {
                    sum += v; sq += v * v;
                    hout[(size_t)grow * NC + col] = f2bf(v);
                }
            }
        }
        sum += __shfl_xor(sum, 16); sum += __shfl_xor(sum, 32);
        sq  += __shfl_xor(sq, 16);  sq  += __shfl_xor(sq, 32);
        if (lgrp == 0) { redsum[wr * 128 + col] = sum; redsq[wr * 128 + col] = sq; }
    }
    __syncthreads();
    if (t < 128) {
        psum[(size_t)blockIdx.x * 128 + t] = redsum[t] + redsum[128 + t];
        psq[(size_t)blockIdx.x * 128 + t]  = redsq[t]  + redsq[128 + t];
    }
}

// ---- single-launch deterministic BN stats: block = channel, butterfly reduce ----
__global__ void bn_stats_kernel(const float* __restrict__ psum, const float* __restrict__ psq,
                                const float* __restrict__ gamma, const float* __restrict__ beta,
                                float* __restrict__ scale, float* __restrict__ shift)
{
    const int c = blockIdx.x;     // 128 channels
    const int t = threadIdx.x;    // 128 threads
    float s = 0.f, q = 0.f;
    for (int b = t; b < NBLK; b += 128) {
        s += psum[b * 128 + c];
        q += psq[b * 128 + c];
    }
    // fixed-order butterfly within each wave, then fixed 2-wave combine: deterministic
    #pragma unroll
    for (int o = 1; o < 64; o <<= 1) {
        s += __shfl_xor(s, o);
        q += __shfl_xor(q, o);
    }
    __shared__ float ls[2], lq[2];
    if ((t & 63) == 0) { ls[t >> 6] = s; lq[t >> 6] = q; }
    __syncthreads();
    if (t == 0) {
        const float S = ls[0] + ls[1];
        const float Q = lq[0] + lq[1];
        const float inv  = 1.f / (float)NV;
        const float mean = S * inv;
        const float var  = Q * inv - mean * mean;
        const float sc   = gamma[c] * rsqrtf(var + BN_EPS);
        scale[c] = sc;
        shift[c] = beta[c] - mean * sc;
    }
}

// ---- apply BN1 + leaky, bf16 -> bf16 ----
__global__ void bn_apply_kernel(const unsigned short* __restrict__ h, const float* __restrict__ scale,
                                const float* __restrict__ shift, unsigned short* __restrict__ outbf)
{
    __shared__ float ssc[NC], ssh[NC];
    if (threadIdx.x < NC) { ssc[threadIdx.x] = scale[threadIdx.x]; ssh[threadIdx.x] = shift[threadIdx.x]; }
    __syncthreads();
    const int total8 = NV * NC / 8;
    for (int i = blockIdx.x * blockDim.x + threadIdx.x; i < total8; i += gridDim.x * blockDim.x) {
        const int e = i * 8;
        const int c0 = e & (NC - 1);
        u16x8 v = *(const u16x8*)(h + e);
        u16x8 o;
        #pragma unroll
        for (int j = 0; j < 8; ++j) {
            float a = bf2f(v[j]) * ssc[c0 + j] + ssh[c0 + j];
            a = a >= 0.f ? a : 0.2f * a;
            o[j] = f2bf(a);
        }
        *(u16x8*)(outbf + e) = o;
    }
}

// ---- final: out = leaky(bn2(h2_bf16) + residual); residual from bf16 x if use_bf ----
__global__ void final_kernel(const unsigned short* __restrict__ h, const float* __restrict__ x,
                             const unsigned short* __restrict__ xb, const int use_bf,
                             const float* __restrict__ scale, const float* __restrict__ shift,
                             float* __restrict__ out)
{
    __shared__ float ssc[NC], ssh[NC];
    if (threadIdx.x < NC) { ssc[threadIdx.x] = scale[threadIdx.x]; ssh[threadIdx.x] = shift[threadIdx.x]; }
    __syncthreads();
    const int total8 = NV * NC / 8;
    for (int i = blockIdx.x * blockDim.x + threadIdx.x; i < total8; i += gridDim.x * blockDim.x) {
        const int e = i * 8;
        const int c0 = e & (NC - 1);
        u16x8 v = *(const u16x8*)(h + e);
        float xv[8];
        if (use_bf) {
            u16x8 xvb = *(const u16x8*)(xb + e);
            #pragma unroll
            for (int j = 0; j < 8; ++j) xv[j] = bf2f(xvb[j]);
        } else {
            float4 x0 = *(const float4*)(x + e);
            float4 x1 = *(const float4*)(x + e + 4);
            xv[0]=x0.x; xv[1]=x0.y; xv[2]=x0.z; xv[3]=x0.w;
            xv[4]=x1.x; xv[5]=x1.y; xv[6]=x1.z; xv[7]=x1.w;
        }
        float ov[8];
        #pragma unroll
        for (int j = 0; j < 8; ++j) {
            float a = bf2f(v[j]) * ssc[c0 + j] + ssh[c0 + j] + xv[j];
            ov[j] = a >= 0.f ? a : 0.2f * a;
        }
        float4 o0 = {ov[0], ov[1], ov[2], ov[3]};
        float4 o1 = {ov[4], ov[5], ov[6], ov[7]};
        *(float4*)(out + e)     = o0;
        *(float4*)(out + e + 4) = o1;
    }
}

extern "C" void kernel_launch(void* const* d_in, const int* in_sizes, int n_in,
                              void* d_out, int out_size, void* d_ws, size_t ws_size,
                              hipStream_t stream)
{
    const float* x      = (const float*)d_in[0];
    const int*   neigh  = (const int*)d_in[1];
    const float* W1     = (const float*)d_in[2];
    // d_in[3] = b1 (cancels through BN)
    const float* gamma1 = (const float*)d_in[4];
    const float* beta1  = (const float*)d_in[5];
    const float* W2     = (const float*)d_in[6];
    // d_in[7] = b2 (cancels through BN)
    const float* gamma2 = (const float*)d_in[8];
    const float* beta2  = (const float*)d_in[9];

    // d_out (84MB fp32) doubles as two bf16 scratch halves until final_kernel.
    unsigned short* h1pre = (unsigned short*)d_out;                    // bf16 [NV][128]
    unsigned short* h1bn  = (unsigned short*)d_out + (size_t)NV * NC;  // bf16 [NV][128]
    float* out = (float*)d_out;

    char* ws = (char*)d_ws;
    size_t off = 0;
    unsigned short* xbf  = (unsigned short*)(ws + off); off += (size_t)NV * NC * 2;
    unsigned short* w1bf = (unsigned short*)(ws + off); off += NWELT * 2;
    unsigned short* w2bf = (unsigned short*)(ws + off); off += NWELT * 2;
    float* psum  = (float*)(ws + off); off += (size_t)NBLK * 128 * 4;
    float* psq   = (float*)(ws + off); off += (size_t)NBLK * 128 * 4;
    float* scale1 = (float*)(ws + off); off += 512;
    float* shift1 = (float*)(ws + off); off += 512;
    float* scale2 = (float*)(ws + off); off += 512;
    float* shift2 = (float*)(ws + off); off += 512;

    // If ws has room for a dedicated h2 buffer, keep xbf alive and use bf16 x
    // for the residual (saves 42MB of fp32 x re-read). Deterministic in ws_size.
    const size_t h2_bytes = (size_t)NV * NC * 2;
    unsigned short* h2pre;
    int use_bf;
    if (off + h2_bytes <= ws_size) { h2pre = (unsigned short*)(ws + off); use_bf = 1; }
    else                           { h2pre = xbf;                        use_bf = 0; }

    cvt_kernel<<<2048, 256, 0, stream>>>(x, W1, W2, xbf, w1bf, w2bf);
    conv_kernel<<<NBLK, 512, 0, stream>>>(xbf, neigh, w1bf, h1pre, psum, psq);
    bn_stats_kernel<<<128, 128, 0, stream>>>(psum, psq, gamma1, beta1, scale1, shift1);
    bn_apply_kernel<<<2048, 256, 0, stream>>>(h1pre, scale1, shift1, h1bn);
    conv_kernel<<<NBLK, 512, 0, stream>>>(h1bn, neigh, w2bf, h2pre, psum, psq);
    bn_stats_kernel<<<128, 128, 0, stream>>>(psum, psq, gamma2, beta2, scale2, shift2);
    final_kernel<<<2048, 256, 0, stream>>>(h2pre, x, xbf, use_bf, scale2, shift2, out);
}

// Round 10
// 185.493 us; speedup vs baseline: 1.1978x; 1.0086x over previous
//
#include <hip/hip_runtime.h>

#define NV 163842          // vertices
#define NC 128             // channels
#define KN 7               // neighbors (incl. self)
#define NWELT (NC * KN * NC)  // 114688 elements per W
#define BN_EPS 1e-5f
#define NBLK 1281          // ceil(NV/128)

typedef __attribute__((ext_vector_type(4))) float f32x4;
typedef __attribute__((ext_vector_type(8))) short bf16x8;
typedef __attribute__((ext_vector_type(8))) unsigned short u16x8;

static __device__ __forceinline__ unsigned short f2bf(float f) {
    union { float f; unsigned int u; } v; v.f = f;
    unsigned int r = v.u + 0x7fffu + ((v.u >> 16) & 1u);
    return (unsigned short)(r >> 16);
}
static __device__ __forceinline__ float bf2f(unsigned short s) {
    union { unsigned int u; float f; } v; v.u = ((unsigned int)s) << 16;
    return v.f;
}
static __device__ __forceinline__ void gload_lds16(const void* g, void* l) {
    __builtin_amdgcn_global_load_lds((const __attribute__((address_space(1))) void*)g,
                                     (__attribute__((address_space(3))) void*)l, 16, 0, 0);
}
// BN+leaky on a packed bf16 pair (elems 2t,2t+1 in one u32), repack via HW cvt_pk (RNE)
static __device__ __forceinline__ unsigned int bn_pair(unsigned int u, float s0, float t0,
                                                       float s1, float t1) {
    float lo = __uint_as_float(u << 16);
    float hi = __uint_as_float(u & 0xffff0000u);
    float a = fmaf(lo, s0, t0);
    float b = fmaf(hi, s1, t1);
    a = fmaxf(a, 0.f) + 0.2f * fminf(a, 0.f);
    b = fmaxf(b, 0.f) + 0.2f * fminf(b, 0.f);
    unsigned int r;
    asm("v_cvt_pk_bf16_f32 %0, %1, %2" : "=v"(r) : "v"(a), "v"(b));
    return r;
}

// ---- kernel 1: fp32 -> bf16 for x, W1, W2 ----
__global__ void cvt_kernel(const float* __restrict__ x, const float* __restrict__ w1,
                           const float* __restrict__ w2, unsigned short* __restrict__ xbf,
                           unsigned short* __restrict__ w1bf, unsigned short* __restrict__ w2bf)
{
    const int total4 = (NV * NC + 2 * NWELT) / 4;
    for (int i = blockIdx.x * blockDim.x + threadIdx.x; i < total4; i += gridDim.x * blockDim.x) {
        int e = i * 4;
        const float* src; unsigned short* dst;
        if (e < NV * NC)              { src = x  + e;                  dst = xbf  + e; }
        else if (e < NV * NC + NWELT) { src = w1 + (e - NV * NC);      dst = w1bf + (e - NV * NC); }
        else                          { src = w2 + (e - NV * NC - NWELT); dst = w2bf + (e - NV * NC - NWELT); }
        float4 v = *(const float4*)src;
        ushort4 o;
        o.x = f2bf(v.x); o.y = f2bf(v.y); o.z = f2bf(v.z); o.w = f2bf(v.w);
        *(ushort4*)dst = o;
    }
}

// ---- conv1: gathered bf16 GEMM, R3-exact structure (measured 59.8us) ----
__global__ __launch_bounds__(512, 4)
void conv_kernel(const unsigned short* __restrict__ xin,   // bf16 [NV][128]
                 const int* __restrict__ neigh,            // [NV*7]
                 const unsigned short* __restrict__ wbf,   // bf16 [128][896]
                 unsigned short* __restrict__ hout,        // bf16 [NV][128]
                 float* __restrict__ psum, float* __restrict__ psq)  // [NBLK][128]
{
    __shared__ __align__(16) char smem[65536];

    const int t    = threadIdx.x;
    const int row0 = blockIdx.x * 128;
    const int w    = t >> 6;
    const int lane = t & 63;
    const int lrow = lane & 15;
    const int lgrp = lane >> 4;
    const int wr   = w >> 2;
    const int wc   = w & 3;

    const int sl   = lane & 7;
    const int r3   = lane >> 3;
    const int srcoff = (sl ^ r3) << 4;

    const int rA0 = w * 16 + r3;
    const int g0  = (row0 + rA0     < NV) ? (row0 + rA0)     : (NV - 1);
    const int g1  = (row0 + rA0 + 8 < NV) ? (row0 + rA0 + 8) : (NV - 1);

    int idx0[KN], idx1[KN];
    #pragma unroll
    for (int k = 0; k < KN; ++k) {
        idx0[k] = neigh[g0 * KN + k];
        idx1[k] = neigh[g1 * KN + k];
    }

    const char* xinb = (const char*)xin;
    const char* bsrc0 = (const char*)wbf + (size_t)(w * 16 + r3) * 1792 + srcoff;
    const char* bsrc1 = (const char*)wbf + (size_t)(w * 16 + 8 + r3) * 1792 + srcoff;

    f32x4 acc[4][2];
    #pragma unroll
    for (int mf = 0; mf < 4; ++mf)
        #pragma unroll
        for (int nf = 0; nf < 2; ++nf)
            acc[mf][nf] = (f32x4){0.f, 0.f, 0.f, 0.f};

#define STAGE(c) do {                                                              \
        const int h_ = (c) & 1, k_ = (c) >> 1, bs_ = ((c) & 1) * 32768;            \
        char* lA = smem + bs_ + w * 2048;                                          \
        char* lB = smem + bs_ + 16384 + w * 2048;                                  \
        gload_lds16(xinb + (size_t)idx0[k_] * 256 + h_ * 128 + srcoff, lA);        \
        gload_lds16(xinb + (size_t)idx1[k_] * 256 + h_ * 128 + srcoff, lA + 1024); \
        gload_lds16(bsrc0 + k_ * 256 + h_ * 128, lB);                              \
        gload_lds16(bsrc1 + k_ * 256 + h_ * 128, lB + 1024);                       \
    } while (0)

    STAGE(0);
    asm volatile("s_waitcnt vmcnt(0)" ::: "memory");
    __builtin_amdgcn_s_barrier();
    __builtin_amdgcn_sched_barrier(0);

    #pragma unroll
    for (int c = 0; c < 14; ++c) {
        if (c < 13) STAGE(c + 1);

        const char* Ab = smem + (c & 1) * 32768;
        const char* Bb = Ab + 16384;
        #pragma unroll
        for (int ks = 0; ks < 2; ++ks) {
            const int koff = ks * 64 + lgrp * 16;
            bf16x8 a[4], b[2];
            #pragma unroll
            for (int mf = 0; mf < 4; ++mf) {
                const int arow = wr * 64 + mf * 16 + lrow;
                a[mf] = *(const bf16x8*)(Ab + ((arow * 128 + koff) ^ ((arow & 7) << 4)));
            }
            #pragma unroll
            for (int nf = 0; nf < 2; ++nf) {
                const int bcol = wc * 32 + nf * 16 + lrow;
                b[nf] = *(const bf16x8*)(Bb + ((bcol * 128 + koff) ^ ((bcol & 7) << 4)));
            }
            #pragma unroll
            for (int mf = 0; mf < 4; ++mf) {
                acc[mf][0] = __builtin_amdgcn_mfma_f32_16x16x32_bf16(a[mf], b[0], acc[mf][0], 0, 0, 0);
                acc[mf][1] = __builtin_amdgcn_mfma_f32_16x16x32_bf16(a[mf], b[1], acc[mf][1], 0, 0, 0);
            }
        }

        if (c < 13) {
            asm volatile("s_waitcnt vmcnt(0)" ::: "memory");
            __builtin_amdgcn_sched_barrier(0);
            __builtin_amdgcn_s_barrier();
            __builtin_amdgcn_sched_barrier(0);
        }
    }
#undef STAGE

    float* redsum = (float*)smem;            // [2][128]
    float* redsq  = (float*)(smem + 1024);   // [2][128]

    #pragma unroll
    for (int nf = 0; nf < 2; ++nf) {
        const int col = wc * 32 + nf * 16 + lrow;
        float sum = 0.f, sq = 0.f;
        #pragma unroll
        for (int mf = 0; mf < 4; ++mf) {
            const int rbase = row0 + wr * 64 + mf * 16 + lgrp * 4;
            #pragma unroll
            for (int r = 0; r < 4; ++r) {
                float v = acc[mf][nf][r];
                const int grow = rbase + r;
                if (grow < NV) {
                    sum += v; sq += v * v;
                    hout[(size_t)grow * NC + col] = f2bf(v);
                }
            }
        }
        sum += __shfl_xor(sum, 16); sum += __shfl_xor(sum, 32);
        sq  += __shfl_xor(sq, 16);  sq  += __shfl_xor(sq, 32);
        if (lgrp == 0) { redsum[wr * 128 + col] = sum; redsq[wr * 128 + col] = sq; }
    }
    __syncthreads();
    if (t < 128) {
        psum[(size_t)blockIdx.x * 128 + t] = redsum[t] + redsum[128 + t];
        psq[(size_t)blockIdx.x * 128 + t]  = redsq[t]  + redsq[128 + t];
    }
}

// ---- conv2: same GEMM but A = leaky(bn1(h1pre)) applied in-register during staging.
// A rows reg-staged (same coalesced 16B/lane pattern), BN+leaky in VGPRs, ds_write
// to lA + lane*16 (matching gload_lds's implicit base+lane*16 layout — rule #21).
__global__ __launch_bounds__(512, 4)
void conv_fused_kernel(const unsigned short* __restrict__ xin,   // h1pre bf16 [NV][128]
                 const int* __restrict__ neigh,
                 const unsigned short* __restrict__ wbf,
                 const float* __restrict__ scale, const float* __restrict__ shift,
                 unsigned short* __restrict__ hout,
                 float* __restrict__ psum, float* __restrict__ psq)
{
    __shared__ __align__(16) char smem[65536];

    const int t    = threadIdx.x;
    const int row0 = blockIdx.x * 128;
    const int w    = t >> 6;
    const int lane = t & 63;
    const int lrow = lane & 15;
    const int lgrp = lane >> 4;
    const int wr   = w >> 2;
    const int wc   = w & 3;

    const int sl   = lane & 7;
    const int r3   = lane >> 3;
    const int srcoff = (sl ^ r3) << 4;

    const int rA0 = w * 16 + r3;
    const int g0  = (row0 + rA0     < NV) ? (row0 + rA0)     : (NV - 1);
    const int g1  = (row0 + rA0 + 8 < NV) ? (row0 + rA0 + 8) : (NV - 1);

    int idx0[KN], idx1[KN];
    #pragma unroll
    for (int k = 0; k < KN; ++k) {
        idx0[k] = neigh[g0 * KN + k];
        idx1[k] = neigh[g1 * KN + k];
    }

    // per-lane BN params: this lane always stages channels h_*64 + cb + [0,8)
    const int cb = (sl ^ r3) * 8;
    float sc[2][8], sh[2][8];
    #pragma unroll
    for (int j = 0; j < 8; ++j) {
        sc[0][j] = scale[cb + j];       sh[0][j] = shift[cb + j];
        sc[1][j] = scale[64 + cb + j];  sh[1][j] = shift[64 + cb + j];
    }

    const char* xinb = (const char*)xin;
    const char* bsrc0 = (const char*)wbf + (size_t)(w * 16 + r3) * 1792 + srcoff;
    const char* bsrc1 = (const char*)wbf + (size_t)(w * 16 + 8 + r3) * 1792 + srcoff;

    f32x4 acc[4][2];
    #pragma unroll
    for (int mf = 0; mf < 4; ++mf)
        #pragma unroll
        for (int nf = 0; nf < 2; ++nf)
            acc[mf][nf] = (f32x4){0.f, 0.f, 0.f, 0.f};

    // prologue: stage chunk 0 (transform path)
    {
        uint4 sa0 = *(const uint4*)(xinb + (size_t)idx0[0] * 256 + srcoff);
        uint4 sa1 = *(const uint4*)(xinb + (size_t)idx1[0] * 256 + srcoff);
        gload_lds16(bsrc0, smem + 16384 + w * 2048);
        gload_lds16(bsrc1, smem + 16384 + w * 2048 + 1024);
        asm volatile("s_waitcnt vmcnt(2)" ::: "memory");
        __builtin_amdgcn_sched_barrier(0);
        char* lA = smem + w * 2048 + lane * 16;          // per-lane dest (== gload_lds layout)
        uint4 o0, o1;
        o0.x = bn_pair(sa0.x, sc[0][0], sh[0][0], sc[0][1], sh[0][1]);
        o0.y = bn_pair(sa0.y, sc[0][2], sh[0][2], sc[0][3], sh[0][3]);
        o0.z = bn_pair(sa0.z, sc[0][4], sh[0][4], sc[0][5], sh[0][5]);
        o0.w = bn_pair(sa0.w, sc[0][6], sh[0][6], sc[0][7], sh[0][7]);
        o1.x = bn_pair(sa1.x, sc[0][0], sh[0][0], sc[0][1], sh[0][1]);
        o1.y = bn_pair(sa1.y, sc[0][2], sh[0][2], sc[0][3], sh[0][3]);
        o1.z = bn_pair(sa1.z, sc[0][4], sh[0][4], sc[0][5], sh[0][5]);
        o1.w = bn_pair(sa1.w, sc[0][6], sh[0][6], sc[0][7], sh[0][7]);
        *(uint4*)lA          = o0;
        *(uint4*)(lA + 1024) = o1;
        asm volatile("s_waitcnt vmcnt(0)" ::: "memory");
        asm volatile("s_waitcnt lgkmcnt(0)" ::: "memory");
        __builtin_amdgcn_sched_barrier(0);
        __builtin_amdgcn_s_barrier();
        __builtin_amdgcn_sched_barrier(0);
    }

    #pragma unroll
    for (int c = 0; c < 14; ++c) {
        uint4 sa0, sa1;
        if (c < 13) {
            const int k_ = (c + 1) >> 1, h_ = (c + 1) & 1, bs_ = ((c + 1) & 1) * 32768;
            sa0 = *(const uint4*)(xinb + (size_t)idx0[k_] * 256 + h_ * 128 + srcoff);
            sa1 = *(const uint4*)(xinb + (size_t)idx1[k_] * 256 + h_ * 128 + srcoff);
            gload_lds16(bsrc0 + k_ * 256 + h_ * 128, smem + bs_ + 16384 + w * 2048);
            gload_lds16(bsrc1 + k_ * 256 + h_ * 128, smem + bs_ + 16384 + w * 2048 + 1024);
        }

        const char* Ab = smem + (c & 1) * 32768;
        const char* Bb = Ab + 16384;
        #pragma unroll
        for (int ks = 0; ks < 2; ++ks) {
            const int koff = ks * 64 + lgrp * 16;
            bf16x8 a[4], b[2];
            #pragma unroll
            for (int mf = 0; mf < 4; ++mf) {
                const int arow = wr * 64 + mf * 16 + lrow;
                a[mf] = *(const bf16x8*)(Ab + ((arow * 128 + koff) ^ ((arow & 7) << 4)));
            }
            #pragma unroll
            for (int nf = 0; nf < 2; ++nf) {
                const int bcol = wc * 32 + nf * 16 + lrow;
                b[nf] = *(const bf16x8*)(Bb + ((bcol * 128 + koff) ^ ((bcol & 7) << 4)));
            }
            #pragma unroll
            for (int mf = 0; mf < 4; ++mf) {
                acc[mf][0] = __builtin_amdgcn_mfma_f32_16x16x32_bf16(a[mf], b[0], acc[mf][0], 0, 0, 0);
                acc[mf][1] = __builtin_amdgcn_mfma_f32_16x16x32_bf16(a[mf], b[1], acc[mf][1], 0, 0, 0);
            }
        }

        if (c < 13) {
            const int hn = (c + 1) & 1, bs_ = ((c + 1) & 1) * 32768;
            asm volatile("s_waitcnt vmcnt(2)" ::: "memory");   // A reg-loads done; B gload_lds in flight
            __builtin_amdgcn_sched_barrier(0);
            char* lA = smem + bs_ + w * 2048 + lane * 16;      // per-lane dest (== gload_lds layout)
            uint4 o0, o1;
            o0.x = bn_pair(sa0.x, sc[hn][0], sh[hn][0], sc[hn][1], sh[hn][1]);
            o0.y = bn_pair(sa0.y, sc[hn][2], sh[hn][2], sc[hn][3], sh[hn][3]);
            o0.z = bn_pair(sa0.z, sc[hn][4], sh[hn][4], sc[hn][5], sh[hn][5]);
            o0.w = bn_pair(sa0.w, sc[hn][6], sh[hn][6], sc[hn][7], sh[hn][7]);
            o1.x = bn_pair(sa1.x, sc[hn][0], sh[hn][0], sc[hn][1], sh[hn][1]);
            o1.y = bn_pair(sa1.y, sc[hn][2], sh[hn][2], sc[hn][3], sh[hn][3]);
            o1.z = bn_pair(sa1.z, sc[hn][4], sh[hn][4], sc[hn][5], sh[hn][5]);
            o1.w = bn_pair(sa1.w, sc[hn][6], sh[hn][6], sc[hn][7], sh[hn][7]);
            *(uint4*)lA          = o0;
            *(uint4*)(lA + 1024) = o1;
            asm volatile("s_waitcnt vmcnt(0)" ::: "memory");   // B staged
            asm volatile("s_waitcnt lgkmcnt(0)" ::: "memory"); // A ds_writes visible
            __builtin_amdgcn_sched_barrier(0);
            __builtin_amdgcn_s_barrier();
            __builtin_amdgcn_sched_barrier(0);
        }
    }

    float* redsum = (float*)smem;            // [2][128]
    float* redsq  = (float*)(smem + 1024);   // [2][128]

    #pragma unroll
    for (int nf = 0; nf < 2; ++nf) {
        const int col = wc * 32 + nf * 16 + lrow;
        float sum = 0.f, sq = 0.f;
        #pragma unroll
        for (int mf = 0; mf < 4; ++mf) {
            const int rbase = row0 + wr * 64 + mf * 16 + lgrp * 4;
            #pragma unroll
            for (int r = 0; r < 4; ++r) {
                float v = acc[mf][nf][r];
                const int grow = rbase + r;
                if (grow < NV) {
                    sum += v; sq += v * v;
                    hout[(size_t)grow * NC + col] = f2bf(v);
                }
            }
        }
        sum += __shfl_xor(sum, 16); sum += __shfl_xor(sum, 32);
        sq  += __shfl_xor(sq, 16);  sq  += __shfl_xor(sq, 32);
        if (lgrp == 0) { redsum[wr * 128 + col] = sum; redsq[wr * 128 + col] = sq; }
    }
    __syncthreads();
    if (t < 128) {
        psum[(size_t)blockIdx.x * 128 + t] = redsum[t] + redsum[128 + t];
        psq[(size_t)blockIdx.x * 128 + t]  = redsq[t]  + redsq[128 + t];
    }
}

// ---- single-launch deterministic BN stats: block = channel, butterfly reduce ----
__global__ void bn_stats_kernel(const float* __restrict__ psum, const float* __restrict__ psq,
                                const float* __restrict__ gamma, const float* __restrict__ beta,
                                float* __restrict__ scale, float* __restrict__ shift)
{
    const int c = blockIdx.x;     // 128 channels
    const int t = threadIdx.x;    // 128 threads
    float s = 0.f, q = 0.f;
    for (int b = t; b < NBLK; b += 128) {
        s += psum[b * 128 + c];
        q += psq[b * 128 + c];
    }
    #pragma unroll
    for (int o = 1; o < 64; o <<= 1) {
        s += __shfl_xor(s, o);
        q += __shfl_xor(q, o);
    }
    __shared__ float ls[2], lq[2];
    if ((t & 63) == 0) { ls[t >> 6] = s; lq[t >> 6] = q; }
    __syncthreads();
    if (t == 0) {
        const float S = ls[0] + ls[1];
        const float Q = lq[0] + lq[1];
        const float inv  = 1.f / (float)NV;
        const float mean = S * inv;
        const float var  = Q * inv - mean * mean;
        const float sc   = gamma[c] * rsqrtf(var + BN_EPS);
        scale[c] = sc;
        shift[c] = beta[c] - mean * sc;
    }
}

// ---- final: out = leaky(bn2(h2_bf16) + residual); residual from bf16 x if use_bf ----
__global__ void final_kernel(const unsigned short* __restrict__ h, const float* __restrict__ x,
                             const unsigned short* __restrict__ xb, const int use_bf,
                             const float* __restrict__ scale, const float* __restrict__ shift,
                             float* __restrict__ out)
{
    __shared__ float ssc[NC], ssh[NC];
    if (threadIdx.x < NC) { ssc[threadIdx.x] = scale[threadIdx.x]; ssh[threadIdx.x] = shift[threadIdx.x]; }
    __syncthreads();
    const int total8 = NV * NC / 8;
    for (int i = blockIdx.x * blockDim.x + threadIdx.x; i < total8; i += gridDim.x * blockDim.x) {
        const int e = i * 8;
        const int c0 = e & (NC - 1);
        u16x8 v = *(const u16x8*)(h + e);
        float xv[8];
        if (use_bf) {
            u16x8 xvb = *(const u16x8*)(xb + e);
            #pragma unroll
            for (int j = 0; j < 8; ++j) xv[j] = bf2f(xvb[j]);
        } else {
            float4 x0 = *(const float4*)(x + e);
            float4 x1 = *(const float4*)(x + e + 4);
            xv[0]=x0.x; xv[1]=x0.y; xv[2]=x0.z; xv[3]=x0.w;
            xv[4]=x1.x; xv[5]=x1.y; xv[6]=x1.z; xv[7]=x1.w;
        }
        float ov[8];
        #pragma unroll
        for (int j = 0; j < 8; ++j) {
            float a = bf2f(v[j]) * ssc[c0 + j] + ssh[c0 + j] + xv[j];
            ov[j] = a >= 0.f ? a : 0.2f * a;
        }
        float4 o0 = {ov[0], ov[1], ov[2], ov[3]};
        float4 o1 = {ov[4], ov[5], ov[6], ov[7]};
        *(float4*)(out + e)     = o0;
        *(float4*)(out + e + 4) = o1;
    }
}

extern "C" void kernel_launch(void* const* d_in, const int* in_sizes, int n_in,
                              void* d_out, int out_size, void* d_ws, size_t ws_size,
                              hipStream_t stream)
{
    const float* x      = (const float*)d_in[0];
    const int*   neigh  = (const int*)d_in[1];
    const float* W1     = (const float*)d_in[2];
    // d_in[3] = b1 (cancels through BN)
    const float* gamma1 = (const float*)d_in[4];
    const float* beta1  = (const float*)d_in[5];
    const float* W2     = (const float*)d_in[6];
    // d_in[7] = b2 (cancels through BN)
    const float* gamma2 = (const float*)d_in[8];
    const float* beta2  = (const float*)d_in[9];

    // d_out (84MB fp32) holds h1pre (bf16) until final_kernel overwrites with fp32 out.
    unsigned short* h1pre = (unsigned short*)d_out;
    float* out = (float*)d_out;

    char* ws = (char*)d_ws;
    size_t off = 0;
    unsigned short* xbf  = (unsigned short*)(ws + off); off += (size_t)NV * NC * 2;
    unsigned short* w1bf = (unsigned short*)(ws + off); off += NWELT * 2;
    unsigned short* w2bf = (unsigned short*)(ws + off); off += NWELT * 2;
    float* psum  = (float*)(ws + off); off += (size_t)NBLK * 128 * 4;
    float* psq   = (float*)(ws + off); off += (size_t)NBLK * 128 * 4;
    float* scale1 = (float*)(ws + off); off += 512;
    float* shift1 = (float*)(ws + off); off += 512;
    float* scale2 = (float*)(ws + off); off += 512;
    float* shift2 = (float*)(ws + off); off += 512;

    // Dedicated h2 buffer if ws permits -> keep xbf alive for bf16 residual.
    const size_t h2_bytes = (size_t)NV * NC * 2;
    unsigned short* h2pre;
    int use_bf;
    if (off + h2_bytes <= ws_size) { h2pre = (unsigned short*)(ws + off); use_bf = 1; }
    else                           { h2pre = xbf;                        use_bf = 0; }

    cvt_kernel<<<2048, 256, 0, stream>>>(x, W1, W2, xbf, w1bf, w2bf);
    conv_kernel<<<NBLK, 512, 0, stream>>>(xbf, neigh, w1bf, h1pre, psum, psq);
    bn_stats_kernel<<<128, 128, 0, stream>>>(psum, psq, gamma1, beta1, scale1, shift1);
    conv_fused_kernel<<<NBLK, 512, 0, stream>>>(h1pre, neigh, w2bf, scale1, shift1, h2pre, psum, psq);
    bn_stats_kernel<<<128, 128, 0, stream>>>(psum, psq, gamma2, beta2, scale2, shift2);
    final_kernel<<<2048, 256, 0, stream>>>(h2pre, x, xbf, use_bf, scale2, shift2, out);
}

// Round 11
// 184.765 us; speedup vs baseline: 1.2025x; 1.0039x over previous
//
#include <hip/hip_runtime.h>

#define NV 163842          // vertices
#define NC 128             // channels
#define KN 7               // neighbors (incl. self)
#define NWELT (NC * KN * NC)  // 114688 elements per W
#define BN_EPS 1e-5f
#define NBLK 1281          // ceil(NV/128)

typedef __attribute__((ext_vector_type(4))) float f32x4;
typedef __attribute__((ext_vector_type(8))) short bf16x8;
typedef __attribute__((ext_vector_type(8))) unsigned short u16x8;

static __device__ __forceinline__ unsigned short f2bf(float f) {
    union { float f; unsigned int u; } v; v.f = f;
    unsigned int r = v.u + 0x7fffu + ((v.u >> 16) & 1u);
    return (unsigned short)(r >> 16);
}
static __device__ __forceinline__ float bf2f(unsigned short s) {
    union { unsigned int u; float f; } v; v.u = ((unsigned int)s) << 16;
    return v.f;
}
static __device__ __forceinline__ void gload_lds16(const void* g, void* l) {
    __builtin_amdgcn_global_load_lds((const __attribute__((address_space(1))) void*)g,
                                     (__attribute__((address_space(3))) void*)l, 16, 0, 0);
}
// BN+leaky on a packed bf16 pair (elems 2t,2t+1 in one u32), repack via HW cvt_pk (RNE)
static __device__ __forceinline__ unsigned int bn_pair(unsigned int u, float s0, float t0,
                                                       float s1, float t1) {
    float lo = __uint_as_float(u << 16);
    float hi = __uint_as_float(u & 0xffff0000u);
    float a = fmaf(lo, s0, t0);
    float b = fmaf(hi, s1, t1);
    a = fmaxf(a, 0.f) + 0.2f * fminf(a, 0.f);
    b = fmaxf(b, 0.f) + 0.2f * fminf(b, 0.f);
    unsigned int r;
    asm("v_cvt_pk_bf16_f32 %0, %1, %2" : "=v"(r) : "v"(a), "v"(b));
    return r;
}

// ---- kernel 1: fp32 -> bf16 for x, W1, W2 ----
__global__ void cvt_kernel(const float* __restrict__ x, const float* __restrict__ w1,
                           const float* __restrict__ w2, unsigned short* __restrict__ xbf,
                           unsigned short* __restrict__ w1bf, unsigned short* __restrict__ w2bf)
{
    const int total4 = (NV * NC + 2 * NWELT) / 4;
    for (int i = blockIdx.x * blockDim.x + threadIdx.x; i < total4; i += gridDim.x * blockDim.x) {
        int e = i * 4;
        const float* src; unsigned short* dst;
        if (e < NV * NC)              { src = x  + e;                  dst = xbf  + e; }
        else if (e < NV * NC + NWELT) { src = w1 + (e - NV * NC);      dst = w1bf + (e - NV * NC); }
        else                          { src = w2 + (e - NV * NC - NWELT); dst = w2bf + (e - NV * NC - NWELT); }
        float4 v = *(const float4*)src;
        ushort4 o;
        o.x = f2bf(v.x); o.y = f2bf(v.y); o.z = f2bf(v.z); o.w = f2bf(v.w);
        *(ushort4*)dst = o;
    }
}

// ---- conv1: gathered bf16 GEMM, R3-exact structure (measured 59.8us) ----
__global__ __launch_bounds__(512, 4)
void conv_kernel(const unsigned short* __restrict__ xin,   // bf16 [NV][128]
                 const int* __restrict__ neigh,            // [NV*7]
                 const unsigned short* __restrict__ wbf,   // bf16 [128][896]
                 unsigned short* __restrict__ hout,        // bf16 [NV][128]
                 float* __restrict__ psum, float* __restrict__ psq)  // [NBLK][128]
{
    __shared__ __align__(16) char smem[65536];

    const int t    = threadIdx.x;
    const int row0 = blockIdx.x * 128;
    const int w    = t >> 6;
    const int lane = t & 63;
    const int lrow = lane & 15;
    const int lgrp = lane >> 4;
    const int wr   = w >> 2;
    const int wc   = w & 3;

    const int sl   = lane & 7;
    const int r3   = lane >> 3;
    const int srcoff = (sl ^ r3) << 4;

    const int rA0 = w * 16 + r3;
    const int g0  = (row0 + rA0     < NV) ? (row0 + rA0)     : (NV - 1);
    const int g1  = (row0 + rA0 + 8 < NV) ? (row0 + rA0 + 8) : (NV - 1);

    int idx0[KN], idx1[KN];
    #pragma unroll
    for (int k = 0; k < KN; ++k) {
        idx0[k] = neigh[g0 * KN + k];
        idx1[k] = neigh[g1 * KN + k];
    }

    const char* xinb = (const char*)xin;
    const char* bsrc0 = (const char*)wbf + (size_t)(w * 16 + r3) * 1792 + srcoff;
    const char* bsrc1 = (const char*)wbf + (size_t)(w * 16 + 8 + r3) * 1792 + srcoff;

    f32x4 acc[4][2];
    #pragma unroll
    for (int mf = 0; mf < 4; ++mf)
        #pragma unroll
        for (int nf = 0; nf < 2; ++nf)
            acc[mf][nf] = (f32x4){0.f, 0.f, 0.f, 0.f};

#define STAGE(c) do {                                                              \
        const int h_ = (c) & 1, k_ = (c) >> 1, bs_ = ((c) & 1) * 32768;            \
        char* lA = smem + bs_ + w * 2048;                                          \
        char* lB = smem + bs_ + 16384 + w * 2048;                                  \
        gload_lds16(xinb + (size_t)idx0[k_] * 256 + h_ * 128 + srcoff, lA);        \
        gload_lds16(xinb + (size_t)idx1[k_] * 256 + h_ * 128 + srcoff, lA + 1024); \
        gload_lds16(bsrc0 + k_ * 256 + h_ * 128, lB);                              \
        gload_lds16(bsrc1 + k_ * 256 + h_ * 128, lB + 1024);                       \
    } while (0)

    STAGE(0);
    asm volatile("s_waitcnt vmcnt(0)" ::: "memory");
    __builtin_amdgcn_s_barrier();
    __builtin_amdgcn_sched_barrier(0);

    #pragma unroll
    for (int c = 0; c < 14; ++c) {
        if (c < 13) STAGE(c + 1);

        const char* Ab = smem + (c & 1) * 32768;
        const char* Bb = Ab + 16384;
        #pragma unroll
        for (int ks = 0; ks < 2; ++ks) {
            const int koff = ks * 64 + lgrp * 16;
            bf16x8 a[4], b[2];
            #pragma unroll
            for (int mf = 0; mf < 4; ++mf) {
                const int arow = wr * 64 + mf * 16 + lrow;
                a[mf] = *(const bf16x8*)(Ab + ((arow * 128 + koff) ^ ((arow & 7) << 4)));
            }
            #pragma unroll
            for (int nf = 0; nf < 2; ++nf) {
                const int bcol = wc * 32 + nf * 16 + lrow;
                b[nf] = *(const bf16x8*)(Bb + ((bcol * 128 + koff) ^ ((bcol & 7) << 4)));
            }
            #pragma unroll
            for (int mf = 0; mf < 4; ++mf) {
                acc[mf][0] = __builtin_amdgcn_mfma_f32_16x16x32_bf16(a[mf], b[0], acc[mf][0], 0, 0, 0);
                acc[mf][1] = __builtin_amdgcn_mfma_f32_16x16x32_bf16(a[mf], b[1], acc[mf][1], 0, 0, 0);
            }
        }

        if (c < 13) {
            asm volatile("s_waitcnt vmcnt(0)" ::: "memory");
            __builtin_amdgcn_sched_barrier(0);
            __builtin_amdgcn_s_barrier();
            __builtin_amdgcn_sched_barrier(0);
        }
    }
#undef STAGE

    float* redsum = (float*)smem;            // [2][128]
    float* redsq  = (float*)(smem + 1024);   // [2][128]

    #pragma unroll
    for (int nf = 0; nf < 2; ++nf) {
        const int col = wc * 32 + nf * 16 + lrow;
        float sum = 0.f, sq = 0.f;
        #pragma unroll
        for (int mf = 0; mf < 4; ++mf) {
            const int rbase = row0 + wr * 64 + mf * 16 + lgrp * 4;
            #pragma unroll
            for (int r = 0; r < 4; ++r) {
                float v = acc[mf][nf][r];
                const int grow = rbase + r;
                if (grow < NV) {
                    sum += v; sq += v * v;
                    hout[(size_t)grow * NC + col] = f2bf(v);
                }
            }
        }
        sum += __shfl_xor(sum, 16); sum += __shfl_xor(sum, 32);
        sq  += __shfl_xor(sq, 16);  sq  += __shfl_xor(sq, 32);
        if (lgrp == 0) { redsum[wr * 128 + col] = sum; redsq[wr * 128 + col] = sq; }
    }
    __syncthreads();
    if (t < 128) {
        psum[(size_t)blockIdx.x * 128 + t] = redsum[t] + redsum[128 + t];
        psq[(size_t)blockIdx.x * 128 + t]  = redsq[t]  + redsq[128 + t];
    }
}

// ---- conv2: A = leaky(bn1(h1pre)) applied in-register during staging.
// Transform placed BETWEEN the two ks MFMA halves (serial tail hidden under MFMA);
// compiler-tracked waits for the reg loads (no manual vmcnt(2)/fences there).
__global__ __launch_bounds__(512, 4)
void conv_fused_kernel(const unsigned short* __restrict__ xin,   // h1pre bf16 [NV][128]
                 const int* __restrict__ neigh,
                 const unsigned short* __restrict__ wbf,
                 const float* __restrict__ scale, const float* __restrict__ shift,
                 unsigned short* __restrict__ hout,
                 float* __restrict__ psum, float* __restrict__ psq)
{
    __shared__ __align__(16) char smem[65536];

    const int t    = threadIdx.x;
    const int row0 = blockIdx.x * 128;
    const int w    = t >> 6;
    const int lane = t & 63;
    const int lrow = lane & 15;
    const int lgrp = lane >> 4;
    const int wr   = w >> 2;
    const int wc   = w & 3;

    const int sl   = lane & 7;
    const int r3   = lane >> 3;
    const int srcoff = (sl ^ r3) << 4;

    const int rA0 = w * 16 + r3;
    const int g0  = (row0 + rA0     < NV) ? (row0 + rA0)     : (NV - 1);
    const int g1  = (row0 + rA0 + 8 < NV) ? (row0 + rA0 + 8) : (NV - 1);

    int idx0[KN], idx1[KN];
    #pragma unroll
    for (int k = 0; k < KN; ++k) {
        idx0[k] = neigh[g0 * KN + k];
        idx1[k] = neigh[g1 * KN + k];
    }

    // per-lane BN params: this lane always stages channels h_*64 + cb + [0,8)
    const int cb = (sl ^ r3) * 8;
    float sc[2][8], sh[2][8];
    #pragma unroll
    for (int j = 0; j < 8; ++j) {
        sc[0][j] = scale[cb + j];       sh[0][j] = shift[cb + j];
        sc[1][j] = scale[64 + cb + j];  sh[1][j] = shift[64 + cb + j];
    }

    const char* xinb = (const char*)xin;
    const char* bsrc0 = (const char*)wbf + (size_t)(w * 16 + r3) * 1792 + srcoff;
    const char* bsrc1 = (const char*)wbf + (size_t)(w * 16 + 8 + r3) * 1792 + srcoff;

    f32x4 acc[4][2];
    #pragma unroll
    for (int mf = 0; mf < 4; ++mf)
        #pragma unroll
        for (int nf = 0; nf < 2; ++nf)
            acc[mf][nf] = (f32x4){0.f, 0.f, 0.f, 0.f};

    // prologue: stage chunk 0 (transform path)
    {
        uint4 sa0 = *(const uint4*)(xinb + (size_t)idx0[0] * 256 + srcoff);
        uint4 sa1 = *(const uint4*)(xinb + (size_t)idx1[0] * 256 + srcoff);
        gload_lds16(bsrc0, smem + 16384 + w * 2048);
        gload_lds16(bsrc1, smem + 16384 + w * 2048 + 1024);
        char* lA = smem + w * 2048 + lane * 16;          // per-lane dest (== gload_lds layout)
        uint4 o0, o1;
        o0.x = bn_pair(sa0.x, sc[0][0], sh[0][0], sc[0][1], sh[0][1]);
        o0.y = bn_pair(sa0.y, sc[0][2], sh[0][2], sc[0][3], sh[0][3]);
        o0.z = bn_pair(sa0.z, sc[0][4], sh[0][4], sc[0][5], sh[0][5]);
        o0.w = bn_pair(sa0.w, sc[0][6], sh[0][6], sc[0][7], sh[0][7]);
        o1.x = bn_pair(sa1.x, sc[0][0], sh[0][0], sc[0][1], sh[0][1]);
        o1.y = bn_pair(sa1.y, sc[0][2], sh[0][2], sc[0][3], sh[0][3]);
        o1.z = bn_pair(sa1.z, sc[0][4], sh[0][4], sc[0][5], sh[0][5]);
        o1.w = bn_pair(sa1.w, sc[0][6], sh[0][6], sc[0][7], sh[0][7]);
        *(uint4*)lA          = o0;
        *(uint4*)(lA + 1024) = o1;
        asm volatile("s_waitcnt vmcnt(0)" ::: "memory");
        asm volatile("s_waitcnt lgkmcnt(0)" ::: "memory");
        __builtin_amdgcn_sched_barrier(0);
        __builtin_amdgcn_s_barrier();
        __builtin_amdgcn_sched_barrier(0);
    }

    #pragma unroll
    for (int c = 0; c < 14; ++c) {
        uint4 sa0, sa1;
        if (c < 13) {
            const int k_ = (c + 1) >> 1, h_ = (c + 1) & 1, bs_ = ((c + 1) & 1) * 32768;
            sa0 = *(const uint4*)(xinb + (size_t)idx0[k_] * 256 + h_ * 128 + srcoff);
            sa1 = *(const uint4*)(xinb + (size_t)idx1[k_] * 256 + h_ * 128 + srcoff);
            gload_lds16(bsrc0 + k_ * 256 + h_ * 128, smem + bs_ + 16384 + w * 2048);
            gload_lds16(bsrc1 + k_ * 256 + h_ * 128, smem + bs_ + 16384 + w * 2048 + 1024);
        }

        const char* Ab = smem + (c & 1) * 32768;
        const char* Bb = Ab + 16384;

        // ---- MFMA ks=0 ----
        {
            const int koff = lgrp * 16;
            bf16x8 a[4], b[2];
            #pragma unroll
            for (int mf = 0; mf < 4; ++mf) {
                const int arow = wr * 64 + mf * 16 + lrow;
                a[mf] = *(const bf16x8*)(Ab + ((arow * 128 + koff) ^ ((arow & 7) << 4)));
            }
            #pragma unroll
            for (int nf = 0; nf < 2; ++nf) {
                const int bcol = wc * 32 + nf * 16 + lrow;
                b[nf] = *(const bf16x8*)(Bb + ((bcol * 128 + koff) ^ ((bcol & 7) << 4)));
            }
            #pragma unroll
            for (int mf = 0; mf < 4; ++mf) {
                acc[mf][0] = __builtin_amdgcn_mfma_f32_16x16x32_bf16(a[mf], b[0], acc[mf][0], 0, 0, 0);
                acc[mf][1] = __builtin_amdgcn_mfma_f32_16x16x32_bf16(a[mf], b[1], acc[mf][1], 0, 0, 0);
            }
        }

        // ---- transform + ds_write for chunk c+1 (other buffer; its previous
        // readers finished before the end-of-iter-(c-1) barrier). Compiler inserts
        // the exact vmcnt for sa0/sa1; MFMA ks=1 below hides the write. ----
        if (c < 13) {
            const int hn = (c + 1) & 1, bs_ = hn * 32768;
            char* lA = smem + bs_ + w * 2048 + lane * 16;
            uint4 o0, o1;
            o0.x = bn_pair(sa0.x, sc[hn][0], sh[hn][0], sc[hn][1], sh[hn][1]);
            o0.y = bn_pair(sa0.y, sc[hn][2], sh[hn][2], sc[hn][3], sh[hn][3]);
            o0.z = bn_pair(sa0.z, sc[hn][4], sh[hn][4], sc[hn][5], sh[hn][5]);
            o0.w = bn_pair(sa0.w, sc[hn][6], sh[hn][6], sc[hn][7], sh[hn][7]);
            o1.x = bn_pair(sa1.x, sc[hn][0], sh[hn][0], sc[hn][1], sh[hn][1]);
            o1.y = bn_pair(sa1.y, sc[hn][2], sh[hn][2], sc[hn][3], sh[hn][3]);
            o1.z = bn_pair(sa1.z, sc[hn][4], sh[hn][4], sc[hn][5], sh[hn][5]);
            o1.w = bn_pair(sa1.w, sc[hn][6], sh[hn][6], sc[hn][7], sh[hn][7]);
            *(uint4*)lA          = o0;
            *(uint4*)(lA + 1024) = o1;
        }

        // ---- MFMA ks=1 ----
        {
            const int koff = 64 + lgrp * 16;
            bf16x8 a[4], b[2];
            #pragma unroll
            for (int mf = 0; mf < 4; ++mf) {
                const int arow = wr * 64 + mf * 16 + lrow;
                a[mf] = *(const bf16x8*)(Ab + ((arow * 128 + koff) ^ ((arow & 7) << 4)));
            }
            #pragma unroll
            for (int nf = 0; nf < 2; ++nf) {
                const int bcol = wc * 32 + nf * 16 + lrow;
                b[nf] = *(const bf16x8*)(Bb + ((bcol * 128 + koff) ^ ((bcol & 7) << 4)));
            }
            #pragma unroll
            for (int mf = 0; mf < 4; ++mf) {
                acc[mf][0] = __builtin_amdgcn_mfma_f32_16x16x32_bf16(a[mf], b[0], acc[mf][0], 0, 0, 0);
                acc[mf][1] = __builtin_amdgcn_mfma_f32_16x16x32_bf16(a[mf], b[1], acc[mf][1], 0, 0, 0);
            }
        }

        if (c < 13) {
            asm volatile("s_waitcnt vmcnt(0)" ::: "memory");   // B gload_lds staged
            asm volatile("s_waitcnt lgkmcnt(0)" ::: "memory"); // A ds_writes visible
            __builtin_amdgcn_sched_barrier(0);
            __builtin_amdgcn_s_barrier();
            __builtin_amdgcn_sched_barrier(0);
        }
    }

    float* redsum = (float*)smem;            // [2][128]
    float* redsq  = (float*)(smem + 1024);   // [2][128]

    #pragma unroll
    for (int nf = 0; nf < 2; ++nf) {
        const int col = wc * 32 + nf * 16 + lrow;
        float sum = 0.f, sq = 0.f;
        #pragma unroll
        for (int mf = 0; mf < 4; ++mf) {
            const int rbase = row0 + wr * 64 + mf * 16 + lgrp * 4;
            #pragma unroll
            for (int r = 0; r < 4; ++r) {
                float v = acc[mf][nf][r];
                const int grow = rbase + r;
                if (grow < NV) {
                    sum += v; sq += v * v;
                    hout[(size_t)grow * NC + col] = f2bf(v);
                }
            }
        }
        sum += __shfl_xor(sum, 16); sum += __shfl_xor(sum, 32);
        sq  += __shfl_xor(sq, 16);  sq  += __shfl_xor(sq, 32);
        if (lgrp == 0) { redsum[wr * 128 + col] = sum; redsq[wr * 128 + col] = sq; }
    }
    __syncthreads();
    if (t < 128) {
        psum[(size_t)blockIdx.x * 128 + t] = redsum[t] + redsum[128 + t];
        psq[(size_t)blockIdx.x * 128 + t]  = redsq[t]  + redsq[128 + t];
    }
}

// ---- single-launch deterministic BN stats: block = channel, butterfly reduce ----
__global__ void bn_stats_kernel(const float* __restrict__ psum, const float* __restrict__ psq,
                                const float* __restrict__ gamma, const float* __restrict__ beta,
                                float* __restrict__ scale, float* __restrict__ shift)
{
    const int c = blockIdx.x;     // 128 channels
    const int t = threadIdx.x;    // 128 threads
    float s = 0.f, q = 0.f;
    for (int b = t; b < NBLK; b += 128) {
        s += psum[b * 128 + c];
        q += psq[b * 128 + c];
    }
    #pragma unroll
    for (int o = 1; o < 64; o <<= 1) {
        s += __shfl_xor(s, o);
        q += __shfl_xor(q, o);
    }
    __shared__ float ls[2], lq[2];
    if ((t & 63) == 0) { ls[t >> 6] = s; lq[t >> 6] = q; }
    __syncthreads();
    if (t == 0) {
        const float S = ls[0] + ls[1];
        const float Q = lq[0] + lq[1];
        const float inv  = 1.f / (float)NV;
        const float mean = S * inv;
        const float var  = Q * inv - mean * mean;
        const float sc   = gamma[c] * rsqrtf(var + BN_EPS);
        scale[c] = sc;
        shift[c] = beta[c] - mean * sc;
    }
}

// ---- final: out = leaky(bn2(h2_bf16) + residual); residual from bf16 x if use_bf ----
__global__ void final_kernel(const unsigned short* __restrict__ h, const float* __restrict__ x,
                             const unsigned short* __restrict__ xb, const int use_bf,
                             const float* __restrict__ scale, const float* __restrict__ shift,
                             float* __restrict__ out)
{
    __shared__ float ssc[NC], ssh[NC];
    if (threadIdx.x < NC) { ssc[threadIdx.x] = scale[threadIdx.x]; ssh[threadIdx.x] = shift[threadIdx.x]; }
    __syncthreads();
    const int total8 = NV * NC / 8;
    for (int i = blockIdx.x * blockDim.x + threadIdx.x; i < total8; i += gridDim.x * blockDim.x) {
        const int e = i * 8;
        const int c0 = e & (NC - 1);
        u16x8 v = *(const u16x8*)(h + e);
        float xv[8];
        if (use_bf) {
            u16x8 xvb = *(const u16x8*)(xb + e);
            #pragma unroll
            for (int j = 0; j < 8; ++j) xv[j] = bf2f(xvb[j]);
        } else {
            float4 x0 = *(const float4*)(x + e);
            float4 x1 = *(const float4*)(x + e + 4);
            xv[0]=x0.x; xv[1]=x0.y; xv[2]=x0.z; xv[3]=x0.w;
            xv[4]=x1.x; xv[5]=x1.y; xv[6]=x1.z; xv[7]=x1.w;
        }
        float ov[8];
        #pragma unroll
        for (int j = 0; j < 8; ++j) {
            float a = bf2f(v[j]) * ssc[c0 + j] + ssh[c0 + j] + xv[j];
            ov[j] = a >= 0.f ? a : 0.2f * a;
        }
        float4 o0 = {ov[0], ov[1], ov[2], ov[3]};
        float4 o1 = {ov[4], ov[5], ov[6], ov[7]};
        *(float4*)(out + e)     = o0;
        *(float4*)(out + e + 4) = o1;
    }
}

extern "C" void kernel_launch(void* const* d_in, const int* in_sizes, int n_in,
                              void* d_out, int out_size, void* d_ws, size_t ws_size,
                              hipStream_t stream)
{
    const float* x      = (const float*)d_in[0];
    const int*   neigh  = (const int*)d_in[1];
    const float* W1     = (const float*)d_in[2];
    // d_in[3] = b1 (cancels through BN)
    const float* gamma1 = (const float*)d_in[4];
    const float* beta1  = (const float*)d_in[5];
    const float* W2     = (const float*)d_in[6];
    // d_in[7] = b2 (cancels through BN)
    const float* gamma2 = (const float*)d_in[8];
    const float* beta2  = (const float*)d_in[9];

    // d_out (84MB fp32) holds h1pre (bf16) until final_kernel overwrites with fp32 out.
    unsigned short* h1pre = (unsigned short*)d_out;
    float* out = (float*)d_out;

    char* ws = (char*)d_ws;
    size_t off = 0;
    unsigned short* xbf  = (unsigned short*)(ws + off); off += (size_t)NV * NC * 2;
    unsigned short* w1bf = (unsigned short*)(ws + off); off += NWELT * 2;
    unsigned short* w2bf = (unsigned short*)(ws + off); off += NWELT * 2;
    float* psum  = (float*)(ws + off); off += (size_t)NBLK * 128 * 4;
    float* psq   = (float*)(ws + off); off += (size_t)NBLK * 128 * 4;
    float* scale1 = (float*)(ws + off); off += 512;
    float* shift1 = (float*)(ws + off); off += 512;
    float* scale2 = (float*)(ws + off); off += 512;
    float* shift2 = (float*)(ws + off); off += 512;

    // Dedicated h2 buffer if ws permits -> keep xbf alive for bf16 residual.
    const size_t h2_bytes = (size_t)NV * NC * 2;
    unsigned short* h2pre;
    int use_bf;
    if (off + h2_bytes <= ws_size) { h2pre = (unsigned short*)(ws + off); use_bf = 1; }
    else                           { h2pre = xbf;                        use_bf = 0; }

    cvt_kernel<<<2048, 256, 0, stream>>>(x, W1, W2, xbf, w1bf, w2bf);
    conv_kernel<<<NBLK, 512, 0, stream>>>(xbf, neigh, w1bf, h1pre, psum, psq);
    bn_stats_kernel<<<128, 128, 0, stream>>>(psum, psq, gamma1, beta1, scale1, shift1);
    conv_fused_kernel<<<NBLK, 512, 0, stream>>>(h1pre, neigh, w2bf, scale1, shift1, h2pre, psum, psq);
    bn_stats_kernel<<<128, 128, 0, stream>>>(psum, psq, gamma2, beta2, scale2, shift2);
    final_kernel<<<2048, 256, 0, stream>>>(h2pre, x, xbf, use_bf, scale2, shift2, out);
}

// Round 12
// 183.642 us; speedup vs baseline: 1.2099x; 1.0061x over previous
//
#include <hip/hip_runtime.h>

#define NV 163842          // vertices
#define NC 128             // channels
#define KN 7               // neighbors (incl. self)
#define NWELT (NC * KN * NC)  // 114688 elements per W
#define BN_EPS 1e-5f
#define NBLK 1281          // ceil(NV/128)

typedef __attribute__((ext_vector_type(4))) float f32x4;
typedef __attribute__((ext_vector_type(8))) short bf16x8;
typedef __attribute__((ext_vector_type(8))) unsigned short u16x8;

static __device__ __forceinline__ unsigned short f2bf(float f) {
    union { float f; unsigned int u; } v; v.f = f;
    unsigned int r = v.u + 0x7fffu + ((v.u >> 16) & 1u);
    return (unsigned short)(r >> 16);
}
static __device__ __forceinline__ float bf2f(unsigned short s) {
    union { unsigned int u; float f; } v; v.u = ((unsigned int)s) << 16;
    return v.f;
}
static __device__ __forceinline__ void gload_lds16(const void* g, void* l) {
    __builtin_amdgcn_global_load_lds((const __attribute__((address_space(1))) void*)g,
                                     (__attribute__((address_space(3))) void*)l, 16, 0, 0);
}
// BN+leaky on a packed bf16 pair (elems 2t,2t+1 in one u32), repack via HW cvt_pk (RNE)
static __device__ __forceinline__ unsigned int bn_pair(unsigned int u, float s0, float t0,
                                                       float s1, float t1) {
    float lo = __uint_as_float(u << 16);
    float hi = __uint_as_float(u & 0xffff0000u);
    float a = fmaf(lo, s0, t0);
    float b = fmaf(hi, s1, t1);
    a = fmaxf(a, 0.f) + 0.2f * fminf(a, 0.f);
    b = fmaxf(b, 0.f) + 0.2f * fminf(b, 0.f);
    unsigned int r;
    asm("v_cvt_pk_bf16_f32 %0, %1, %2" : "=v"(r) : "v"(a), "v"(b));
    return r;
}

// ---- kernel 1: fp32 -> bf16 for x, W1, W2 ----
__global__ void cvt_kernel(const float* __restrict__ x, const float* __restrict__ w1,
                           const float* __restrict__ w2, unsigned short* __restrict__ xbf,
                           unsigned short* __restrict__ w1bf, unsigned short* __restrict__ w2bf)
{
    const int total4 = (NV * NC + 2 * NWELT) / 4;
    for (int i = blockIdx.x * blockDim.x + threadIdx.x; i < total4; i += gridDim.x * blockDim.x) {
        int e = i * 4;
        const float* src; unsigned short* dst;
        if (e < NV * NC)              { src = x  + e;                  dst = xbf  + e; }
        else if (e < NV * NC + NWELT) { src = w1 + (e - NV * NC);      dst = w1bf + (e - NV * NC); }
        else                          { src = w2 + (e - NV * NC - NWELT); dst = w2bf + (e - NV * NC - NWELT); }
        float4 v = *(const float4*)src;
        ushort4 o;
        o.x = f2bf(v.x); o.y = f2bf(v.y); o.z = f2bf(v.z); o.w = f2bf(v.w);
        *(ushort4*)dst = o;
    }
}

// ---- conv1: gathered bf16 GEMM, R3-exact structure (measured 59.8us) ----
__global__ __launch_bounds__(512, 4)
void conv_kernel(const unsigned short* __restrict__ xin,   // bf16 [NV][128]
                 const int* __restrict__ neigh,            // [NV*7]
                 const unsigned short* __restrict__ wbf,   // bf16 [128][896]
                 unsigned short* __restrict__ hout,        // bf16 [NV][128]
                 float* __restrict__ psum, float* __restrict__ psq)  // [NBLK][128]
{
    __shared__ __align__(16) char smem[65536];

    const int t    = threadIdx.x;
    const int row0 = blockIdx.x * 128;
    const int w    = t >> 6;
    const int lane = t & 63;
    const int lrow = lane & 15;
    const int lgrp = lane >> 4;
    const int wr   = w >> 2;
    const int wc   = w & 3;

    const int sl   = lane & 7;
    const int r3   = lane >> 3;
    const int srcoff = (sl ^ r3) << 4;

    const int rA0 = w * 16 + r3;
    const int g0  = (row0 + rA0     < NV) ? (row0 + rA0)     : (NV - 1);
    const int g1  = (row0 + rA0 + 8 < NV) ? (row0 + rA0 + 8) : (NV - 1);

    int idx0[KN], idx1[KN];
    #pragma unroll
    for (int k = 0; k < KN; ++k) {
        idx0[k] = neigh[g0 * KN + k];
        idx1[k] = neigh[g1 * KN + k];
    }

    const char* xinb = (const char*)xin;
    const char* bsrc0 = (const char*)wbf + (size_t)(w * 16 + r3) * 1792 + srcoff;
    const char* bsrc1 = (const char*)wbf + (size_t)(w * 16 + 8 + r3) * 1792 + srcoff;

    f32x4 acc[4][2];
    #pragma unroll
    for (int mf = 0; mf < 4; ++mf)
        #pragma unroll
        for (int nf = 0; nf < 2; ++nf)
            acc[mf][nf] = (f32x4){0.f, 0.f, 0.f, 0.f};

#define STAGE(c) do {                                                              \
        const int h_ = (c) & 1, k_ = (c) >> 1, bs_ = ((c) & 1) * 32768;            \
        char* lA = smem + bs_ + w * 2048;                                          \
        char* lB = smem + bs_ + 16384 + w * 2048;                                  \
        gload_lds16(xinb + (size_t)idx0[k_] * 256 + h_ * 128 + srcoff, lA);        \
        gload_lds16(xinb + (size_t)idx1[k_] * 256 + h_ * 128 + srcoff, lA + 1024); \
        gload_lds16(bsrc0 + k_ * 256 + h_ * 128, lB);                              \
        gload_lds16(bsrc1 + k_ * 256 + h_ * 128, lB + 1024);                       \
    } while (0)

    STAGE(0);
    asm volatile("s_waitcnt vmcnt(0)" ::: "memory");
    __builtin_amdgcn_s_barrier();
    __builtin_amdgcn_sched_barrier(0);

    #pragma unroll
    for (int c = 0; c < 14; ++c) {
        if (c < 13) STAGE(c + 1);

        const char* Ab = smem + (c & 1) * 32768;
        const char* Bb = Ab + 16384;
        #pragma unroll
        for (int ks = 0; ks < 2; ++ks) {
            const int koff = ks * 64 + lgrp * 16;
            bf16x8 a[4], b[2];
            #pragma unroll
            for (int mf = 0; mf < 4; ++mf) {
                const int arow = wr * 64 + mf * 16 + lrow;
                a[mf] = *(const bf16x8*)(Ab + ((arow * 128 + koff) ^ ((arow & 7) << 4)));
            }
            #pragma unroll
            for (int nf = 0; nf < 2; ++nf) {
                const int bcol = wc * 32 + nf * 16 + lrow;
                b[nf] = *(const bf16x8*)(Bb + ((bcol * 128 + koff) ^ ((bcol & 7) << 4)));
            }
            #pragma unroll
            for (int mf = 0; mf < 4; ++mf) {
                acc[mf][0] = __builtin_amdgcn_mfma_f32_16x16x32_bf16(a[mf], b[0], acc[mf][0], 0, 0, 0);
                acc[mf][1] = __builtin_amdgcn_mfma_f32_16x16x32_bf16(a[mf], b[1], acc[mf][1], 0, 0, 0);
            }
        }

        if (c < 13) {
            asm volatile("s_waitcnt vmcnt(0)" ::: "memory");
            __builtin_amdgcn_sched_barrier(0);
            __builtin_amdgcn_s_barrier();
            __builtin_amdgcn_sched_barrier(0);
        }
    }
#undef STAGE

    float* redsum = (float*)smem;            // [2][128]
    float* redsq  = (float*)(smem + 1024);   // [2][128]

    #pragma unroll
    for (int nf = 0; nf < 2; ++nf) {
        const int col = wc * 32 + nf * 16 + lrow;
        float sum = 0.f, sq = 0.f;
        #pragma unroll
        for (int mf = 0; mf < 4; ++mf) {
            const int rbase = row0 + wr * 64 + mf * 16 + lgrp * 4;
            #pragma unroll
            for (int r = 0; r < 4; ++r) {
                float v = acc[mf][nf][r];
                const int grow = rbase + r;
                if (grow < NV) {
                    sum += v; sq += v * v;
                    hout[(size_t)grow * NC + col] = f2bf(v);
                }
            }
        }
        sum += __shfl_xor(sum, 16); sum += __shfl_xor(sum, 32);
        sq  += __shfl_xor(sq, 16);  sq  += __shfl_xor(sq, 32);
        if (lgrp == 0) { redsum[wr * 128 + col] = sum; redsq[wr * 128 + col] = sq; }
    }
    __syncthreads();
    if (t < 128) {
        psum[(size_t)blockIdx.x * 128 + t] = redsum[t] + redsum[128 + t];
        psq[(size_t)blockIdx.x * 128 + t]  = redsq[t]  + redsq[128 + t];
    }
}

// ---- conv2 (R10 form, measured 71.0us): A = leaky(bn1(h1pre)) in-register during
// staging; transform after the MFMA phase, gated by vmcnt(2); ds_write to
// lA + lane*16 (gload_lds-compatible layout — rule #21).
__global__ __launch_bounds__(512, 4)
void conv_fused_kernel(const unsigned short* __restrict__ xin,   // h1pre bf16 [NV][128]
                 const int* __restrict__ neigh,
                 const unsigned short* __restrict__ wbf,
                 const float* __restrict__ scale, const float* __restrict__ shift,
                 unsigned short* __restrict__ hout,
                 float* __restrict__ psum, float* __restrict__ psq)
{
    __shared__ __align__(16) char smem[65536];

    const int t    = threadIdx.x;
    const int row0 = blockIdx.x * 128;
    const int w    = t >> 6;
    const int lane = t & 63;
    const int lrow = lane & 15;
    const int lgrp = lane >> 4;
    const int wr   = w >> 2;
    const int wc   = w & 3;

    const int sl   = lane & 7;
    const int r3   = lane >> 3;
    const int srcoff = (sl ^ r3) << 4;

    const int rA0 = w * 16 + r3;
    const int g0  = (row0 + rA0     < NV) ? (row0 + rA0)     : (NV - 1);
    const int g1  = (row0 + rA0 + 8 < NV) ? (row0 + rA0 + 8) : (NV - 1);

    int idx0[KN], idx1[KN];
    #pragma unroll
    for (int k = 0; k < KN; ++k) {
        idx0[k] = neigh[g0 * KN + k];
        idx1[k] = neigh[g1 * KN + k];
    }

    // per-lane BN params: this lane always stages channels h_*64 + cb + [0,8)
    const int cb = (sl ^ r3) * 8;
    float sc[2][8], sh[2][8];
    #pragma unroll
    for (int j = 0; j < 8; ++j) {
        sc[0][j] = scale[cb + j];       sh[0][j] = shift[cb + j];
        sc[1][j] = scale[64 + cb + j];  sh[1][j] = shift[64 + cb + j];
    }

    const char* xinb = (const char*)xin;
    const char* bsrc0 = (const char*)wbf + (size_t)(w * 16 + r3) * 1792 + srcoff;
    const char* bsrc1 = (const char*)wbf + (size_t)(w * 16 + 8 + r3) * 1792 + srcoff;

    f32x4 acc[4][2];
    #pragma unroll
    for (int mf = 0; mf < 4; ++mf)
        #pragma unroll
        for (int nf = 0; nf < 2; ++nf)
            acc[mf][nf] = (f32x4){0.f, 0.f, 0.f, 0.f};

    // prologue: stage chunk 0 (transform path)
    {
        uint4 sa0 = *(const uint4*)(xinb + (size_t)idx0[0] * 256 + srcoff);
        uint4 sa1 = *(const uint4*)(xinb + (size_t)idx1[0] * 256 + srcoff);
        gload_lds16(bsrc0, smem + 16384 + w * 2048);
        gload_lds16(bsrc1, smem + 16384 + w * 2048 + 1024);
        asm volatile("s_waitcnt vmcnt(2)" ::: "memory");
        __builtin_amdgcn_sched_barrier(0);
        char* lA = smem + w * 2048 + lane * 16;          // per-lane dest (== gload_lds layout)
        uint4 o0, o1;
        o0.x = bn_pair(sa0.x, sc[0][0], sh[0][0], sc[0][1], sh[0][1]);
        o0.y = bn_pair(sa0.y, sc[0][2], sh[0][2], sc[0][3], sh[0][3]);
        o0.z = bn_pair(sa0.z, sc[0][4], sh[0][4], sc[0][5], sh[0][5]);
        o0.w = bn_pair(sa0.w, sc[0][6], sh[0][6], sc[0][7], sh[0][7]);
        o1.x = bn_pair(sa1.x, sc[0][0], sh[0][0], sc[0][1], sh[0][1]);
        o1.y = bn_pair(sa1.y, sc[0][2], sh[0][2], sc[0][3], sh[0][3]);
        o1.z = bn_pair(sa1.z, sc[0][4], sh[0][4], sc[0][5], sh[0][5]);
        o1.w = bn_pair(sa1.w, sc[0][6], sh[0][6], sc[0][7], sh[0][7]);
        *(uint4*)lA          = o0;
        *(uint4*)(lA + 1024) = o1;
        asm volatile("s_waitcnt vmcnt(0)" ::: "memory");
        asm volatile("s_waitcnt lgkmcnt(0)" ::: "memory");
        __builtin_amdgcn_sched_barrier(0);
        __builtin_amdgcn_s_barrier();
        __builtin_amdgcn_sched_barrier(0);
    }

    #pragma unroll
    for (int c = 0; c < 14; ++c) {
        uint4 sa0, sa1;
        if (c < 13) {
            const int k_ = (c + 1) >> 1, h_ = (c + 1) & 1, bs_ = ((c + 1) & 1) * 32768;
            sa0 = *(const uint4*)(xinb + (size_t)idx0[k_] * 256 + h_ * 128 + srcoff);
            sa1 = *(const uint4*)(xinb + (size_t)idx1[k_] * 256 + h_ * 128 + srcoff);
            gload_lds16(bsrc0 + k_ * 256 + h_ * 128, smem + bs_ + 16384 + w * 2048);
            gload_lds16(bsrc1 + k_ * 256 + h_ * 128, smem + bs_ + 16384 + w * 2048 + 1024);
        }

        const char* Ab = smem + (c & 1) * 32768;
        const char* Bb = Ab + 16384;
        #pragma unroll
        for (int ks = 0; ks < 2; ++ks) {
            const int koff = ks * 64 + lgrp * 16;
            bf16x8 a[4], b[2];
            #pragma unroll
            for (int mf = 0; mf < 4; ++mf) {
                const int arow = wr * 64 + mf * 16 + lrow;
                a[mf] = *(const bf16x8*)(Ab + ((arow * 128 + koff) ^ ((arow & 7) << 4)));
            }
            #pragma unroll
            for (int nf = 0; nf < 2; ++nf) {
                const int bcol = wc * 32 + nf * 16 + lrow;
                b[nf] = *(const bf16x8*)(Bb + ((bcol * 128 + koff) ^ ((bcol & 7) << 4)));
            }
            #pragma unroll
            for (int mf = 0; mf < 4; ++mf) {
                acc[mf][0] = __builtin_amdgcn_mfma_f32_16x16x32_bf16(a[mf], b[0], acc[mf][0], 0, 0, 0);
                acc[mf][1] = __builtin_amdgcn_mfma_f32_16x16x32_bf16(a[mf], b[1], acc[mf][1], 0, 0, 0);
            }
        }

        if (c < 13) {
            const int hn = (c + 1) & 1, bs_ = ((c + 1) & 1) * 32768;
            asm volatile("s_waitcnt vmcnt(2)" ::: "memory");   // A reg-loads done; B gload_lds in flight
            __builtin_amdgcn_sched_barrier(0);
            char* lA = smem + bs_ + w * 2048 + lane * 16;      // per-lane dest (== gload_lds layout)
            uint4 o0, o1;
            o0.x = bn_pair(sa0.x, sc[hn][0], sh[hn][0], sc[hn][1], sh[hn][1]);
            o0.y = bn_pair(sa0.y, sc[hn][2], sh[hn][2], sc[hn][3], sh[hn][3]);
            o0.z = bn_pair(sa0.z, sc[hn][4], sh[hn][4], sc[hn][5], sh[hn][5]);
            o0.w = bn_pair(sa0.w, sc[hn][6], sh[hn][6], sc[hn][7], sh[hn][7]);
            o1.x = bn_pair(sa1.x, sc[hn][0], sh[hn][0], sc[hn][1], sh[hn][1]);
            o1.y = bn_pair(sa1.y, sc[hn][2], sh[hn][2], sc[hn][3], sh[hn][3]);
            o1.z = bn_pair(sa1.z, sc[hn][4], sh[hn][4], sc[hn][5], sh[hn][5]);
            o1.w = bn_pair(sa1.w, sc[hn][6], sh[hn][6], sc[hn][7], sh[hn][7]);
            *(uint4*)lA          = o0;
            *(uint4*)(lA + 1024) = o1;
            asm volatile("s_waitcnt vmcnt(0)" ::: "memory");   // B staged
            asm volatile("s_waitcnt lgkmcnt(0)" ::: "memory"); // A ds_writes visible
            __builtin_amdgcn_sched_barrier(0);
            __builtin_amdgcn_s_barrier();
            __builtin_amdgcn_sched_barrier(0);
        }
    }

    float* redsum = (float*)smem;            // [2][128]
    float* redsq  = (float*)(smem + 1024);   // [2][128]

    #pragma unroll
    for (int nf = 0; nf < 2; ++nf) {
        const int col = wc * 32 + nf * 16 + lrow;
        float sum = 0.f, sq = 0.f;
        #pragma unroll
        for (int mf = 0; mf < 4; ++mf) {
            const int rbase = row0 + wr * 64 + mf * 16 + lgrp * 4;
            #pragma unroll
            for (int r = 0; r < 4; ++r) {
                float v = acc[mf][nf][r];
                const int grow = rbase + r;
                if (grow < NV) {
                    sum += v; sq += v * v;
                    hout[(size_t)grow * NC + col] = f2bf(v);
                }
            }
        }
        sum += __shfl_xor(sum, 16); sum += __shfl_xor(sum, 32);
        sq  += __shfl_xor(sq, 16);  sq  += __shfl_xor(sq, 32);
        if (lgrp == 0) { redsum[wr * 128 + col] = sum; redsq[wr * 128 + col] = sq; }
    }
    __syncthreads();
    if (t < 128) {
        psum[(size_t)blockIdx.x * 128 + t] = redsum[t] + redsum[128 + t];
        psq[(size_t)blockIdx.x * 128 + t]  = redsq[t]  + redsq[128 + t];
    }
}

// ---- single-launch deterministic BN stats: block = channel, butterfly reduce ----
__global__ void bn_stats_kernel(const float* __restrict__ psum, const float* __restrict__ psq,
                                const float* __restrict__ gamma, const float* __restrict__ beta,
                                float* __restrict__ scale, float* __restrict__ shift)
{
    const int c = blockIdx.x;     // 128 channels
    const int t = threadIdx.x;    // 128 threads
    float s = 0.f, q = 0.f;
    for (int b = t; b < NBLK; b += 128) {
        s += psum[b * 128 + c];
        q += psq[b * 128 + c];
    }
    #pragma unroll
    for (int o = 1; o < 64; o <<= 1) {
        s += __shfl_xor(s, o);
        q += __shfl_xor(q, o);
    }
    __shared__ float ls[2], lq[2];
    if ((t & 63) == 0) { ls[t >> 6] = s; lq[t >> 6] = q; }
    __syncthreads();
    if (t == 0) {
        const float S = ls[0] + ls[1];
        const float Q = lq[0] + lq[1];
        const float inv  = 1.f / (float)NV;
        const float mean = S * inv;
        const float var  = Q * inv - mean * mean;
        const float sc   = gamma[c] * rsqrtf(var + BN_EPS);
        scale[c] = sc;
        shift[c] = beta[c] - mean * sc;
    }
}

// ---- final: out = leaky(bn2(h2_bf16) + residual); residual from bf16 x if use_bf ----
__global__ void final_kernel(const unsigned short* __restrict__ h, const float* __restrict__ x,
                             const unsigned short* __restrict__ xb, const int use_bf,
                             const float* __restrict__ scale, const float* __restrict__ shift,
                             float* __restrict__ out)
{
    __shared__ float ssc[NC], ssh[NC];
    if (threadIdx.x < NC) { ssc[threadIdx.x] = scale[threadIdx.x]; ssh[threadIdx.x] = shift[threadIdx.x]; }
    __syncthreads();
    const int total8 = NV * NC / 8;
    for (int i = blockIdx.x * blockDim.x + threadIdx.x; i < total8; i += gridDim.x * blockDim.x) {
        const int e = i * 8;
        const int c0 = e & (NC - 1);
        u16x8 v = *(const u16x8*)(h + e);
        float xv[8];
        if (use_bf) {
            u16x8 xvb = *(const u16x8*)(xb + e);
            #pragma unroll
            for (int j = 0; j < 8; ++j) xv[j] = bf2f(xvb[j]);
        } else {
            float4 x0 = *(const float4*)(x + e);
            float4 x1 = *(const float4*)(x + e + 4);
            xv[0]=x0.x; xv[1]=x0.y; xv[2]=x0.z; xv[3]=x0.w;
            xv[4]=x1.x; xv[5]=x1.y; xv[6]=x1.z; xv[7]=x1.w;
        }
        float ov[8];
        #pragma unroll
        for (int j = 0; j < 8; ++j) {
            float a = bf2f(v[j]) * ssc[c0 + j] + ssh[c0 + j] + xv[j];
            ov[j] = a >= 0.f ? a : 0.2f * a;
        }
        float4 o0 = {ov[0], ov[1], ov[2], ov[3]};
        float4 o1 = {ov[4], ov[5], ov[6], ov[7]};
        *(float4*)(out + e)     = o0;
        *(float4*)(out + e + 4) = o1;
    }
}

extern "C" void kernel_launch(void* const* d_in, const int* in_sizes, int n_in,
                              void* d_out, int out_size, void* d_ws, size_t ws_size,
                              hipStream_t stream)
{
    const float* x      = (const float*)d_in[0];
    const int*   neigh  = (const int*)d_in[1];
    const float* W1     = (const float*)d_in[2];
    // d_in[3] = b1 (cancels through BN)
    const float* gamma1 = (const float*)d_in[4];
    const float* beta1  = (const float*)d_in[5];
    const float* W2     = (const float*)d_in[6];
    // d_in[7] = b2 (cancels through BN)
    const float* gamma2 = (const float*)d_in[8];
    const float* beta2  = (const float*)d_in[9];

    // d_out (84MB fp32) holds h1pre (bf16) until final_kernel overwrites with fp32 out.
    unsigned short* h1pre = (unsigned short*)d_out;
    float* out = (float*)d_out;

    char* ws = (char*)d_ws;
    size_t off = 0;
    unsigned short* xbf  = (unsigned short*)(ws + off); off += (size_t)NV * NC * 2;
    unsigned short* w1bf = (unsigned short*)(ws + off); off += NWELT * 2;
    unsigned short* w2bf = (unsigned short*)(ws + off); off += NWELT * 2;
    float* psum  = (float*)(ws + off); off += (size_t)NBLK * 128 * 4;
    float* psq   = (float*)(ws + off); off += (size_t)NBLK * 128 * 4;
    float* scale1 = (float*)(ws + off); off += 512;
    float* shift1 = (float*)(ws + off); off += 512;
    float* scale2 = (float*)(ws + off); off += 512;
    float* shift2 = (float*)(ws + off); off += 512;

    // Dedicated h2 buffer if ws permits -> keep xbf alive for bf16 residual.
    const size_t h2_bytes = (size_t)NV * NC * 2;
    unsigned short* h2pre;
    int use_bf;
    if (off + h2_bytes <= ws_size) { h2pre = (unsigned short*)(ws + off); use_bf = 1; }
    else                           { h2pre = xbf;                        use_bf = 0; }

    cvt_kernel<<<2048, 256, 0, stream>>>(x, W1, W2, xbf, w1bf, w2bf);
    conv_kernel<<<NBLK, 512, 0, stream>>>(xbf, neigh, w1bf, h1pre, psum, psq);
    bn_stats_kernel<<<128, 128, 0, stream>>>(psum, psq, gamma1, beta1, scale1, shift1);
    conv_fused_kernel<<<NBLK, 512, 0, stream>>>(h1pre, neigh, w2bf, scale1, shift1, h2pre, psum, psq);
    bn_stats_kernel<<<128, 128, 0, stream>>>(psum, psq, gamma2, beta2, scale2, shift2);
    final_kernel<<<2048, 256, 0, stream>>>(h2pre, x, xbf, use_bf, scale2, shift2, out);
}